// Round 18
// baseline (6525.945 us; speedup 1.0000x reference)
//
#include <hip/hip_runtime.h>

typedef unsigned short u16;
typedef float f32x4 __attribute__((ext_vector_type(4)));
typedef __bf16 bf16x8 __attribute__((ext_vector_type(8)));

__device__ __forceinline__ u16 f2b(float f) {
  unsigned u = __builtin_bit_cast(unsigned, f);
  u += 0x7FFF + ((u >> 16) & 1);
  return (u16)(u >> 16);
}

__device__ __forceinline__ float b2f(u16 v) {
  unsigned u = (unsigned)v << 16;
  return __builtin_bit_cast(float, u);
}

__device__ __forceinline__ f32x4 ld_bf4(const u16* p) {
  ushort4 v = *(const ushort4*)p;
  f32x4 r;
  r[0] = b2f(v.x); r[1] = b2f(v.y); r[2] = b2f(v.z); r[3] = b2f(v.w);
  return r;
}

// mish(x) = x * tanh(softplus(x)) = x * (e^2+2e)/(e^2+2e+2), e = exp(x)
__device__ __forceinline__ float mishf(float x) {
  float e = __expf(fminf(x, 20.f));
  float n = e * (e + 2.f);
  return x * __fdividef(n, n + 2.f);
}

__device__ __forceinline__ void gl_lds16(const void* g, void* l) {
  __builtin_amdgcn_global_load_lds((__attribute__((address_space(1))) void*)g,
                                   (__attribute__((address_space(3))) void*)l, 16, 0, 0);
}

__device__ __forceinline__ bf16x8 ldb8(const u16* p) {
  return __builtin_bit_cast(bf16x8, *(const uint4*)p);
}

// ---------------- weight transpose f32[K,N] -> bf16[N,K] ----------------
__global__ __launch_bounds__(256)
void transpose_w(const float* __restrict__ in, u16* __restrict__ out, int K, int N) {
  __shared__ float tl[64][65];
  const long zoff = (long)blockIdx.z * K * N;
  in += zoff; out += zoff;
  const int n0 = blockIdx.x * 64, k0 = blockIdx.y * 64;
  const int c = threadIdx.x & 63, r0 = threadIdx.x >> 6;
#pragma unroll
  for (int i = 0; i < 16; ++i) {
    int r = i * 4 + r0;
    tl[r][c] = in[(long)(k0 + r) * N + n0 + c];
  }
  __syncthreads();
#pragma unroll
  for (int i = 0; i < 16; ++i) {
    int r = i * 4 + r0;
    out[(long)(n0 + r) * K + k0 + c] = f2b(tl[c][r]);
  }
}

// ---------------- concat adaln_b [9216] + fa_b [512] -> f32[9728] ----------------
__global__ __launch_bounds__(256)
void concat_bias(const float* __restrict__ a, const float* __restrict__ b,
                 float* __restrict__ out) {
  int i = blockIdx.x * 256 + threadIdx.x;
  if (i < 9216) out[i] = a[i];
  else if (i < 9728) out[i] = b[i - 9216];
}

// ---------------- timestep-embedding MLP table (21 rows) ----------------
__global__ __launch_bounds__(1024)
void te_table_kernel(const float* __restrict__ emb, const float* __restrict__ w1,
                     const float* __restrict__ b1, const float* __restrict__ w2,
                     const float* __restrict__ b2, float* __restrict__ table) {
  __shared__ float te[256];
  __shared__ float h1[1024];
  __shared__ float red[1024];
  const int tt = blockIdx.x, tid = threadIdx.x;
  if (tid < 256) te[tid] = emb[tt * 256 + tid];
  __syncthreads();
  float a = b1[tid];
#pragma unroll 8
  for (int k = 0; k < 256; ++k) a += te[k] * w1[k * 1024 + tid];
  h1[tid] = mishf(a);
  __syncthreads();
  const int j = tid & 255, kq = tid >> 8;
  float a2 = 0.f;
#pragma unroll 8
  for (int k = kq * 256; k < kq * 256 + 256; ++k) a2 += h1[k] * w2[k * 256 + j];
  red[tid] = a2;
  __syncthreads();
  if (tid < 256)
    table[tt * 256 + tid] = b2[tid] + red[tid] + red[tid + 256] + red[tid + 512] + red[tid + 768];
}

// ---------------- cond = mean over S, written bf16 ----------------
__global__ __launch_bounds__(256)
void cond_mean_kernel(const float* __restrict__ bb, u16* __restrict__ cond) {
  const int b = blockIdx.x, tid = threadIdx.x;
  const float* p = bb + (long)b * 64 * 512;
  for (int d = tid; d < 512; d += 256) {
    float s = 0.f;
#pragma unroll
    for (int t = 0; t < 64; ++t) s += p[t * 512 + d];
    cond[b * 512 + d] = f2b(s * (1.f / 64.f));
  }
}

// ---------------- LayerNorm + adaLN modulate -> bf16 (layer-0 input; mod is bf16) ----------------
__global__ __launch_bounds__(256)
void ln_mod(const float* __restrict__ x, const u16* __restrict__ modb,
            int mstride, int shoff, int scoff, u16* __restrict__ out) {
  const int lane = threadIdx.x & 63;
  const long row = (long)blockIdx.x * 4 + (threadIdx.x >> 6);
  const float4 xv = *(const float4*)(x + row * 256 + lane * 4);
  float s1 = xv.x + xv.y + xv.z + xv.w;
  float s2 = xv.x * xv.x + xv.y * xv.y + xv.z * xv.z + xv.w * xv.w;
#pragma unroll
  for (int m = 1; m < 64; m <<= 1) { s1 += __shfl_xor(s1, m); s2 += __shfl_xor(s2, m); }
  const float mean = s1 * (1.f / 256.f);
  float var = s2 * (1.f / 256.f) - mean * mean;
  const float rstd = rsqrtf(fmaxf(var, 0.f) + 1e-5f);
  const long b = row >> 6;
  const f32x4 sc = ld_bf4(modb + b * mstride + scoff + lane * 4);
  const f32x4 sh = ld_bf4(modb + b * mstride + shoff + lane * 4);
  ushort4 o;
  o.x = f2b((xv.x - mean) * rstd * (1.f + sc[0]) + sh[0]);
  o.y = f2b((xv.y - mean) * rstd * (1.f + sc[1]) + sh[1]);
  o.z = f2b((xv.z - mean) * rstd * (1.f + sc[2]) + sh[2]);
  o.w = f2b((xv.w - mean) * rstd * (1.f + sc[3]) + sh[3]);
  *(ushort4*)(out + row * 256 + lane * 4) = o;
}

// ---------------- GEMM: C[M,N] = A[M,K](bf16) @ Bt[N,K]^T(bf16) + epilogue ----------------
// EPI 0: +bias -> bf16 | 1: mish(+bias) -> bf16 | 3: +bias -> f32
// EPI 4: mish(+bias + te_table[t[row]]) -> bf16
template <int EPI>
__global__ __launch_bounds__(256)
void gemm_bt(const u16* __restrict__ A, const u16* __restrict__ Bt,
             const float* __restrict__ bias, void* __restrict__ outp,
             const int* __restrict__ tvec, const float* __restrict__ tetab,
             int M, int N, int K) {
  __shared__ __align__(16) u16 As[2][128 * 64];
  __shared__ __align__(16) u16 Bs[2][128 * 64];
  const int tid = threadIdx.x;
  const int lane = tid & 63;
  const int wave = tid >> 6;
  const int wr = (wave >> 1) << 6;
  const int wc = (wave & 1) << 6;
  const long tm = (long)blockIdx.y * 128;
  const long tn = (long)blockIdx.x * 128;
  const u16* Ag = A + tm * K;
  const u16* Bg = Bt + tn * K;
  f32x4 acc[4][4] = {};
  const int kcb = lane >> 4;
  const int swz = lane & 7;
  const int NT = K >> 6;

  auto stage = [&](int t, int buf) {
    const int k0 = t << 6;
#pragma unroll
    for (int i = 0; i < 4; ++i) {
      int c = tid + (i << 8);
      int r = c >> 3;
      int sch = (c & 7) ^ (r & 7);
      gl_lds16(Ag + (long)r * K + k0 + (sch << 3), &As[buf][c << 3]);
    }
#pragma unroll
    for (int i = 0; i < 4; ++i) {
      int c = tid + (i << 8);
      int r = c >> 3;
      int sch = (c & 7) ^ (r & 7);
      gl_lds16(Bg + (long)r * K + k0 + (sch << 3), &Bs[buf][c << 3]);
    }
  };

  stage(0, 0);
  __syncthreads();
  int cur = 0;
  for (int t = 0; t < NT; ++t) {
    if (t + 1 < NT) stage(t + 1, cur ^ 1);
#pragma unroll
    for (int kt = 0; kt < 2; ++kt) {
      const int ko = ((kt * 4 + kcb) ^ swz) << 3;
      bf16x8 av[4], bv[4];
#pragma unroll
      for (int mt = 0; mt < 4; ++mt)
        av[mt] = ldb8(&As[cur][(wr + mt * 16 + (lane & 15)) * 64 + ko]);
#pragma unroll
      for (int nt = 0; nt < 4; ++nt)
        bv[nt] = ldb8(&Bs[cur][(wc + nt * 16 + (lane & 15)) * 64 + ko]);
#pragma unroll
      for (int mt = 0; mt < 4; ++mt)
#pragma unroll
        for (int nt = 0; nt < 4; ++nt)
          acc[mt][nt] = __builtin_amdgcn_mfma_f32_16x16x32_bf16(bv[nt], av[mt], acc[mt][nt], 0, 0, 0);
    }
    __syncthreads();
    cur ^= 1;
  }
  const int rl = lane & 15;
  const int c4 = (lane >> 4) << 2;
  f32x4 b4[4];
#pragma unroll
  for (int nt = 0; nt < 4; ++nt)
    b4[nt] = *(const f32x4*)(bias + (int)tn + wc + nt * 16 + c4);
#pragma unroll
  for (int mt = 0; mt < 4; ++mt) {
    const unsigned row = (unsigned)(tm + wr + mt * 16 + rl);
    const unsigned rb = row * (unsigned)N;
#pragma unroll
    for (int nt = 0; nt < 4; ++nt) {
      const unsigned col = (unsigned)tn + wc + nt * 16 + c4;
      f32x4 v = acc[mt][nt] + b4[nt];
      if constexpr (EPI == 0) {
        ushort4 o;
        o.x = f2b(v[0]); o.y = f2b(v[1]); o.z = f2b(v[2]); o.w = f2b(v[3]);
        *(ushort4*)((u16*)outp + rb + col) = o;
      } else if constexpr (EPI == 1) {
        ushort4 o;
        o.x = f2b(mishf(v[0])); o.y = f2b(mishf(v[1]));
        o.z = f2b(mishf(v[2])); o.w = f2b(mishf(v[3]));
        *(ushort4*)((u16*)outp + rb + col) = o;
      } else if constexpr (EPI == 3) {
        *(f32x4*)((float*)outp + rb + col) = v;
      } else {
        const f32x4 te = *(const f32x4*)(tetab + tvec[row] * 256 + col);
        ushort4 o;
        o.x = f2b(mishf(v[0] + te[0])); o.y = f2b(mishf(v[1] + te[1]));
        o.z = f2b(mishf(v[2] + te[2])); o.w = f2b(mishf(v[3] + te[3]));
        *(ushort4*)((u16*)outp + rb + col) = o;
      }
    }
  }
}

// ---------------- GEMM (N=256 full rows) + residual + LayerNorm + modulate ----------------
// TWO batch elems per block, software-pipelined (R15 pattern): elem-1's A/B tile-0
// staged during elem-0's last K-step; stats scratch in the dead A buffer.
template <int K, bool XF32>
__global__ __launch_bounds__(256)
void gemm_ln(const u16* __restrict__ A, const u16* __restrict__ Bt,
             const float* __restrict__ bias, const void* __restrict__ xin,
             const u16* __restrict__ gptr, int gstride,
             const u16* __restrict__ lnsh, const u16* __restrict__ lnsc, int lnstride,
             u16* __restrict__ xout, u16* __restrict__ hout) {
  __shared__ __align__(16) u16 As[2][64 * 64];
  __shared__ __align__(16) u16 Bs[2][256 * 64];
  const int tid = threadIdx.x, lane = tid & 63, wave = tid >> 6;
  const int wc = wave << 6;
  const long b0 = (long)blockIdx.x * 2;
  const int rl = lane & 15;
  const int c4 = (lane >> 4) << 2;
  const int swz = lane & 7;
  const int NT = K >> 6;

  auto stageA = [&](long b, int t, int buf) {
    const u16* Ag = A + b * 64 * K;
    const int k0 = t << 6;
#pragma unroll
    for (int i = 0; i < 2; ++i) {
      int c = tid + (i << 8);
      int r = c >> 3;
      int sch = (c & 7) ^ (r & 7);
      gl_lds16(Ag + (long)r * K + k0 + (sch << 3), &As[buf][c << 3]);
    }
  };
  auto stageB = [&](int t, int buf) {
    const int k0 = t << 6;
#pragma unroll
    for (int i = 0; i < 8; ++i) {
      int c = tid + (i << 8);
      int r = c >> 3;
      int sch = (c & 7) ^ (r & 7);
      gl_lds16(Bt + (long)r * K + k0 + (sch << 3), &Bs[buf][c << 3]);
    }
  };

  stageA(b0, 0, 0);
  stageB(0, 0);
  __syncthreads();
  int cur = 0;

  for (int e = 0; e < 2; ++e) {
    const long b = b0 + e;
    const long tm = b * 64;
    f32x4 acc[4][4] = {};
    for (int t = 0; t < NT; ++t) {
      if (t + 1 < NT) { stageA(b, t + 1, cur ^ 1); stageB(t + 1, cur ^ 1); }
      else if (e == 0) { stageA(b0 + 1, 0, cur ^ 1); stageB(0, cur ^ 1); }
#pragma unroll
      for (int kt = 0; kt < 2; ++kt) {
        const int ko = ((kt * 4 + (lane >> 4)) ^ swz) << 3;
        bf16x8 av[4], bv[4];
#pragma unroll
        for (int mt = 0; mt < 4; ++mt)
          av[mt] = ldb8(&As[cur][(mt * 16 + rl) * 64 + ko]);
#pragma unroll
        for (int nt = 0; nt < 4; ++nt)
          bv[nt] = ldb8(&Bs[cur][(wc + nt * 16 + rl) * 64 + ko]);
#pragma unroll
        for (int mt = 0; mt < 4; ++mt)
#pragma unroll
          for (int nt = 0; nt < 4; ++nt)
            acc[mt][nt] = __builtin_amdgcn_mfma_f32_16x16x32_bf16(bv[nt], av[mt], acc[mt][nt], 0, 0, 0);
      }
      __syncthreads();
      cur ^= 1;
    }

    // epilogue: residual + LN; stats scratch in dead As[cur^1]
    float s1[4] = {}, s2[4] = {};
#pragma unroll
    for (int nt = 0; nt < 4; ++nt) {
      const int col = wc + nt * 16 + c4;
      const f32x4 b4 = *(const f32x4*)(bias + col);
      const f32x4 g4 = ld_bf4(gptr + b * gstride + col);
#pragma unroll
      for (int mt = 0; mt < 4; ++mt) {
        const long row = tm + mt * 16 + rl;
        f32x4 x;
        if constexpr (XF32) x = *(const f32x4*)((const float*)xin + row * 256 + col);
        else x = ld_bf4((const u16*)xin + row * 256 + col);
        f32x4 xn = x + g4 * (acc[mt][nt] + b4);
        acc[mt][nt] = xn;
        s1[mt] += xn[0] + xn[1] + xn[2] + xn[3];
        s2[mt] += xn[0] * xn[0] + xn[1] * xn[1] + xn[2] * xn[2] + xn[3] * xn[3];
      }
    }
#pragma unroll
    for (int mt = 0; mt < 4; ++mt) {
      s1[mt] += __shfl_xor(s1[mt], 16); s1[mt] += __shfl_xor(s1[mt], 32);
      s2[mt] += __shfl_xor(s2[mt], 16); s2[mt] += __shfl_xor(s2[mt], 32);
    }
    float* st = (float*)&As[cur ^ 1][0];
    if (lane < 16) {
#pragma unroll
      for (int mt = 0; mt < 4; ++mt) {
        st[wave * 128 + mt * 16 + lane] = s1[mt];
        st[wave * 128 + 64 + mt * 16 + lane] = s2[mt];
      }
    }
    __syncthreads();
    float mean[4], rstd[4];
#pragma unroll
    for (int mt = 0; mt < 4; ++mt) {
      float a = 0.f, q = 0.f;
#pragma unroll
      for (int w2 = 0; w2 < 4; ++w2) {
        a += st[w2 * 128 + mt * 16 + rl];
        q += st[w2 * 128 + 64 + mt * 16 + rl];
      }
      mean[mt] = a * (1.f / 256.f);
      float var = q * (1.f / 256.f) - mean[mt] * mean[mt];
      rstd[mt] = rsqrtf(fmaxf(var, 0.f) + 1e-5f);
    }
#pragma unroll
    for (int nt = 0; nt < 4; ++nt) {
      const int col = wc + nt * 16 + c4;
      const f32x4 sc4 = ld_bf4(lnsc + b * lnstride + col);
      const f32x4 sh4 = ld_bf4(lnsh + b * lnstride + col);
#pragma unroll
      for (int mt = 0; mt < 4; ++mt) {
        const long row = tm + mt * 16 + rl;
        ushort4 xo;
        xo.x = f2b(acc[mt][nt][0]); xo.y = f2b(acc[mt][nt][1]);
        xo.z = f2b(acc[mt][nt][2]); xo.w = f2b(acc[mt][nt][3]);
        *(ushort4*)(xout + row * 256 + col) = xo;
        f32x4 h = (acc[mt][nt] - mean[mt]) * rstd[mt] * (1.f + sc4) + sh4;
        ushort4 o;
        o.x = f2b(h[0]); o.y = f2b(h[1]); o.z = f2b(h[2]); o.w = f2b(h[3]);
        *(ushort4*)(hout + row * 256 + col) = o;
      }
    }
    __syncthreads();  // protect stats scratch before next elem's staging overwrites As
  }
}

// ---------------- fused FFN: x=x+g2*(mish(xln@W1^T+b1)@W2^T+b2); h=LN(x)*(1+sc)+sh ----------------
// Block processes TWO batch elems, software-pipelined (R15-proven). LDS 160KB (1 block/CU).
__global__ __launch_bounds__(512)
void ffn_fused(const u16* __restrict__ xln, const u16* __restrict__ W1t,
               const float* __restrict__ b1, const u16* __restrict__ W2t,
               const float* __restrict__ b2, const u16* __restrict__ xres,
               const u16* __restrict__ gptr, int gstride,
               const u16* __restrict__ lnsh, const u16* __restrict__ lnsc, int lnstride,
               u16* __restrict__ xout, u16* __restrict__ hout) {
  __shared__ __align__(16) u16 Ax[64 * 256];
  __shared__ __align__(16) u16 Ws[2][256 * 64];
  __shared__ __align__(16) u16 H1[64 * 512];
  const int tid = threadIdx.x, lane = tid & 63, wave = tid >> 6;
  const long b0 = (long)blockIdx.x * 2;
  const int rl = lane & 15;
  const int c4 = (lane >> 4) << 2;
  const int kq = lane >> 4;

  auto stageAx = [&](long b) {
    const u16* src = xln + b * (64 * 256);
#pragma unroll
    for (int i = 0; i < 4; ++i) {
      int c = tid + (i << 9);
      int r = c >> 5, cc = c & 31;
      int sch = (cc & ~7) | ((cc & 7) ^ (r & 7));
      gl_lds16(src + r * 256 + (sch << 3), &Ax[c << 3]);
    }
  };
  auto stageW = [&](const u16* Wsrc, int Kw, int R0, int k0, int buf) {
#pragma unroll
    for (int i = 0; i < 4; ++i) {
      int c = tid + (i << 9);
      int r = c >> 3;
      int sch = (c & 7) ^ (r & 7);
      gl_lds16(Wsrc + (long)(R0 + r) * Kw + k0 + (sch << 3), &Ws[buf][c << 3]);
    }
  };

  stageAx(b0);
  stageW(W1t, 256, 0, 0, 0);
  __syncthreads();
  int cur = 0;

  for (int e = 0; e < 2; ++e) {
    const long b = b0 + e;
    // ---- phase A: h1 = mish(xln @ W1t^T + b1), two 256-col halves ----
    for (int nh = 0; nh < 2; ++nh) {
      f32x4 acc[4][2] = {};
      for (int t = 0; t < 4; ++t) {
        int s = nh * 4 + t;
        if (s < 7) stageW(W1t, 256, ((s + 1) >> 2) * 256, ((s + 1) & 3) * 64, cur ^ 1);
        else stageW(W2t, 512, 0, 0, cur ^ 1);  // prefetch phase-B tile 0
#pragma unroll
        for (int kt = 0; kt < 2; ++kt) {
          bf16x8 av[4], bv[2];
#pragma unroll
          for (int mt = 0; mt < 4; ++mt) {
            int r = mt * 16 + rl;
            int kc = t * 8 + kt * 4 + kq;
            int slot = (kc & ~7) | ((kc & 7) ^ (r & 7));
            av[mt] = ldb8(&Ax[r * 256 + (slot << 3)]);
          }
#pragma unroll
          for (int nf = 0; nf < 2; ++nf) {
            int wr_ = wave * 32 + nf * 16 + rl;
            int slot = (kt * 4 + kq) ^ (wr_ & 7);
            bv[nf] = ldb8(&Ws[cur][wr_ * 64 + (slot << 3)]);
          }
#pragma unroll
          for (int mt = 0; mt < 4; ++mt)
#pragma unroll
            for (int nf = 0; nf < 2; ++nf)
              acc[mt][nf] = __builtin_amdgcn_mfma_f32_16x16x32_bf16(bv[nf], av[mt], acc[mt][nf], 0, 0, 0);
        }
        __syncthreads();
        cur ^= 1;
      }
      // epilogue A: mish -> H1 (swizzled ds_write)
#pragma unroll
      for (int nf = 0; nf < 2; ++nf) {
        const int col = nh * 256 + wave * 32 + nf * 16 + c4;
        const f32x4 bb = *(const f32x4*)(b1 + col);
        const int c8 = col >> 3;
        const int sub = (col & 7) << 1;
#pragma unroll
        for (int mt = 0; mt < 4; ++mt) {
          const int r = mt * 16 + rl;
          f32x4 v = acc[mt][nf] + bb;
          ushort4 o;
          o.x = f2b(mishf(v[0])); o.y = f2b(mishf(v[1]));
          o.z = f2b(mishf(v[2])); o.w = f2b(mishf(v[3]));
          int slot = (c8 & ~7) | ((c8 & 7) ^ (r & 7));
          *(ushort4*)((char*)H1 + r * 1024 + (slot << 4) + sub) = o;
        }
      }
    }
    __syncthreads();  // H1 visible; W2 tile 0 staged; all Ax reads complete

    // ---- phase B: out = h1 @ W2t^T + b2; residual + LN ----
    f32x4 acc[4][2] = {};
    for (int t = 0; t < 8; ++t) {
      if (t < 7) stageW(W2t, 512, 0, (t + 1) * 64, cur ^ 1);
      else if (e == 0) stageW(W1t, 256, 0, 0, cur ^ 1);  // next elem's W1 tile 0
      if (t == 0 && e == 0) stageAx(b0 + 1);             // next elem's x (Ax dead)
#pragma unroll
      for (int kt = 0; kt < 2; ++kt) {
        bf16x8 av[4], bv[2];
#pragma unroll
        for (int mt = 0; mt < 4; ++mt) {
          int r = mt * 16 + rl;
          int kc = t * 8 + kt * 4 + kq;
          int slot = (kc & ~7) | ((kc & 7) ^ (r & 7));
          av[mt] = ldb8((const u16*)((const char*)H1 + r * 1024 + (slot << 4)));
        }
#pragma unroll
        for (int nf = 0; nf < 2; ++nf) {
          int wr_ = wave * 32 + nf * 16 + rl;
          int slot = (kt * 4 + kq) ^ (wr_ & 7);
          bv[nf] = ldb8(&Ws[cur][wr_ * 64 + (slot << 3)]);
        }
#pragma unroll
        for (int mt = 0; mt < 4; ++mt)
#pragma unroll
          for (int nf = 0; nf < 2; ++nf)
            acc[mt][nf] = __builtin_amdgcn_mfma_f32_16x16x32_bf16(bv[nf], av[mt], acc[mt][nf], 0, 0, 0);
      }
      __syncthreads();
      cur ^= 1;
    }
    // residual + row stats (wave's 32-col strip); stats scratch in H1 (dead after phase B)
    float s1[4] = {}, s2[4] = {};
#pragma unroll
    for (int nf = 0; nf < 2; ++nf) {
      const int col = wave * 32 + nf * 16 + c4;
      const f32x4 bb = *(const f32x4*)(b2 + col);
      const f32x4 g4 = ld_bf4(gptr + b * gstride + col);
#pragma unroll
      for (int mt = 0; mt < 4; ++mt) {
        const long row = b * 64 + mt * 16 + rl;
        f32x4 x = ld_bf4(xres + row * 256 + col);
        f32x4 xn = x + g4 * (acc[mt][nf] + bb);
        acc[mt][nf] = xn;
        s1[mt] += xn[0] + xn[1] + xn[2] + xn[3];
        s2[mt] += xn[0] * xn[0] + xn[1] * xn[1] + xn[2] * xn[2] + xn[3] * xn[3];
      }
    }
#pragma unroll
    for (int mt = 0; mt < 4; ++mt) {
      s1[mt] += __shfl_xor(s1[mt], 16); s1[mt] += __shfl_xor(s1[mt], 32);
      s2[mt] += __shfl_xor(s2[mt], 16); s2[mt] += __shfl_xor(s2[mt], 32);
    }
    float* st = (float*)&H1[0];
    if (lane < 16) {
#pragma unroll
      for (int mt = 0; mt < 4; ++mt) {
        st[wave * 128 + mt * 16 + lane] = s1[mt];
        st[wave * 128 + 64 + mt * 16 + lane] = s2[mt];
      }
    }
    __syncthreads();
    float mean[4], rstd[4];
#pragma unroll
    for (int mt = 0; mt < 4; ++mt) {
      float a = 0.f, q = 0.f;
#pragma unroll
      for (int w2 = 0; w2 < 8; ++w2) {
        a += st[w2 * 128 + mt * 16 + rl];
        q += st[w2 * 128 + 64 + mt * 16 + rl];
      }
      mean[mt] = a * (1.f / 256.f);
      float var = q * (1.f / 256.f) - mean[mt] * mean[mt];
      rstd[mt] = rsqrtf(fmaxf(var, 0.f) + 1e-5f);
    }
#pragma unroll
    for (int nf = 0; nf < 2; ++nf) {
      const int col = wave * 32 + nf * 16 + c4;
      const f32x4 sc4 = ld_bf4(lnsc + b * lnstride + col);
      const f32x4 sh4 = ld_bf4(lnsh + b * lnstride + col);
#pragma unroll
      for (int mt = 0; mt < 4; ++mt) {
        const long row = b * 64 + mt * 16 + rl;
        ushort4 xo;
        xo.x = f2b(acc[mt][nf][0]); xo.y = f2b(acc[mt][nf][1]);
        xo.z = f2b(acc[mt][nf][2]); xo.w = f2b(acc[mt][nf][3]);
        *(ushort4*)(xout + row * 256 + col) = xo;
        f32x4 h = (acc[mt][nf] - mean[mt]) * rstd[mt] * (1.f + sc4) + sh4;
        ushort4 o;
        o.x = f2b(h[0]); o.y = f2b(h[1]); o.z = f2b(h[2]); o.w = f2b(h[3]);
        *(ushort4*)(hout + row * 256 + col) = o;
      }
    }
    __syncthreads();  // stats reads done before next elem's epilogue-A overwrites H1
  }
}

// ---------------- fused attention: per (b, head-pair) block, wave=head ----------------
__global__ __launch_bounds__(128)
void attn_kernel(const u16* __restrict__ qkv, u16* __restrict__ out) {
  __shared__ __align__(16) u16 vt_s[2][64 * 72];
  __shared__ __align__(16) u16 p_s[2][64 * 72];
  const int lane = threadIdx.x & 63;
  const int wave = threadIdx.x >> 6;
  const long b = blockIdx.x >> 1;
  const int h = ((blockIdx.x & 1) << 1) | wave;
  u16* vt = vt_s[wave];
  u16* pl = p_s[wave];
  const u16* base = qkv + b * (64 * 768);
#pragma unroll
  for (int it = 0; it < 8; ++it) {
    int chunk = it * 64 + lane;
    int t = chunk >> 3, dhb = (chunk & 7) << 3;
    union { uint4 u; u16 s[8]; } uv;
    uv.u = *(const uint4*)(base + t * 768 + 512 + h * 64 + dhb);
#pragma unroll
    for (int j = 0; j < 8; ++j) vt[(dhb + j) * 72 + t] = uv.s[j];
  }
  const u16* qb = base + h * 64;
  const u16* kb = base + 256 + h * 64;
  f32x4 sacc[4][4] = {};
#pragma unroll
  for (int kt = 0; kt < 2; ++kt) {
    bf16x8 qa[4], kv[4];
#pragma unroll
    for (int mt = 0; mt < 4; ++mt)
      qa[mt] = ldb8(qb + ((lane & 15) + mt * 16) * 768 + kt * 32 + ((lane >> 4) << 3));
#pragma unroll
    for (int nt = 0; nt < 4; ++nt)
      kv[nt] = ldb8(kb + ((lane & 15) + nt * 16) * 768 + kt * 32 + ((lane >> 4) << 3));
#pragma unroll
    for (int mt = 0; mt < 4; ++mt)
#pragma unroll
      for (int nt = 0; nt < 4; ++nt)
        sacc[mt][nt] = __builtin_amdgcn_mfma_f32_16x16x32_bf16(qa[mt], kv[nt], sacc[mt][nt], 0, 0, 0);
  }
  const float scale = 0.125f;
#pragma unroll
  for (int mt = 0; mt < 4; ++mt) {
#pragma unroll
    for (int r = 0; r < 4; ++r) {
      float mx = fmaxf(fmaxf(sacc[mt][0][r], sacc[mt][1][r]), fmaxf(sacc[mt][2][r], sacc[mt][3][r]));
#pragma unroll
      for (int m = 1; m <= 8; m <<= 1) mx = fmaxf(mx, __shfl_xor(mx, m));
      float p[4];
      float sum = 0.f;
#pragma unroll
      for (int nt = 0; nt < 4; ++nt) { p[nt] = __expf((sacc[mt][nt][r] - mx) * scale); sum += p[nt]; }
#pragma unroll
      for (int m = 1; m <= 8; m <<= 1) sum += __shfl_xor(sum, m);
      const float rinv = 1.f / sum;
      const int s = mt * 16 + ((lane >> 4) << 2) + r;
#pragma unroll
      for (int nt = 0; nt < 4; ++nt) pl[s * 72 + nt * 16 + (lane & 15)] = f2b(p[nt] * rinv);
    }
  }
  __syncthreads();
  f32x4 oacc[4][4] = {};
#pragma unroll
  for (int kt = 0; kt < 2; ++kt) {
    bf16x8 pa[4], vv[4];
#pragma unroll
    for (int mt = 0; mt < 4; ++mt)
      pa[mt] = ldb8(pl + ((lane & 15) + mt * 16) * 72 + kt * 32 + ((lane >> 4) << 3));
#pragma unroll
    for (int nt = 0; nt < 4; ++nt)
      vv[nt] = ldb8(vt + ((lane & 15) + nt * 16) * 72 + kt * 32 + ((lane >> 4) << 3));
#pragma unroll
    for (int mt = 0; mt < 4; ++mt)
#pragma unroll
      for (int nt = 0; nt < 4; ++nt)
        oacc[mt][nt] = __builtin_amdgcn_mfma_f32_16x16x32_bf16(vv[nt], pa[mt], oacc[mt][nt], 0, 0, 0);
  }
  u16* ob = out + b * (64 * 256) + h * 64;
#pragma unroll
  for (int mt = 0; mt < 4; ++mt)
#pragma unroll
    for (int nt = 0; nt < 4; ++nt) {
      const int s = mt * 16 + (lane & 15);
      const int d4 = nt * 16 + ((lane >> 4) << 2);
      ushort4 o;
      o.x = f2b(oacc[mt][nt][0]); o.y = f2b(oacc[mt][nt][1]);
      o.z = f2b(oacc[mt][nt][2]); o.w = f2b(oacc[mt][nt][3]);
      *(ushort4*)(ob + s * 256 + d4) = o;
    }
}

extern "C" void kernel_launch(void* const* d_in, const int* in_sizes, int n_in,
                              void* d_out, int out_size, void* d_ws, size_t ws_size,
                              hipStream_t stream) {
  (void)in_sizes; (void)n_in; (void)out_size; (void)ws_size;
  const int B = 4096, L = 6;
  const long BSr = (long)B * 64;

  const float* x_t = (const float*)d_in[0];
  const int* tvec = (const int*)d_in[1];
  const float* backbone = (const float*)d_in[2];
  const float* emb = (const float*)d_in[3];
  const float* te_w1 = (const float*)d_in[4];
  const float* te_b1 = (const float*)d_in[5];
  const float* te_w2 = (const float*)d_in[6];
  const float* te_b2 = (const float*)d_in[7];
  const float* cp_w1 = (const float*)d_in[8];
  const float* cp_b1 = (const float*)d_in[9];
  const float* cp_w2 = (const float*)d_in[10];
  const float* cp_b2 = (const float*)d_in[11];
  const float* adaln_w = (const float*)d_in[12];
  const float* adaln_b = (const float*)d_in[13];
  const float* qkv_w = (const float*)d_in[14];
  const float* qkv_b = (const float*)d_in[15];
  const float* op_w = (const float*)d_in[16];
  const float* op_b = (const float*)d_in[17];
  const float* ffn_w1 = (const float*)d_in[18];
  const float* ffn_b1 = (const float*)d_in[19];
  const float* ffn_w2 = (const float*)d_in[20];
  const float* ffn_b2 = (const float*)d_in[21];
  const float* fa_w = (const float*)d_in[22];
  const float* fa_b = (const float*)d_in[23];
  const float* fp_w = (const float*)d_in[24];
  const float* fp_b = (const float*)d_in[25];

  char* w = (char*)d_ws;
  auto alloc = [&](size_t bytes) { char* p = w; w += (bytes + 255) & ~(size_t)255; return p; };
  u16* WT_cp1 = (u16*)alloc(256L * 512 * 2);
  u16* WT_cp2 = (u16*)alloc(256L * 256 * 2);
  u16* WT_all = (u16*)alloc(9728L * 256 * 2);   // adaln [9216][256] + fa [512][256]
  u16* WT_qkv = (u16*)alloc(6L * 768 * 256 * 2);
  u16* WT_op = (u16*)alloc(6L * 256 * 256 * 2);
  u16* WT_f1 = (u16*)alloc(6L * 512 * 256 * 2);
  u16* WT_f2 = (u16*)alloc(6L * 256 * 512 * 2);
  u16* WT_fp = (u16*)alloc(256L * 256 * 2);
  float* bias_all = (float*)alloc(9728L * 4);
  float* te_tab = (float*)alloc(21L * 256 * 4);
  u16* cond = (u16*)alloc(4096L * 512 * 2);
  u16* c1 = (u16*)alloc(4096L * 256 * 2);
  u16* mc = (u16*)alloc(4096L * 256 * 2);
  u16* modb6 = (u16*)alloc(4096L * 9728 * 2);  // batch-major [4096][6*1536 + 512]
  u16* hbuf = (u16*)alloc(BSr * 256 * 2);
  u16* qkvbuf = (u16*)alloc(BSr * 768 * 2);
  u16* xbuf = (u16*)d_out;  // bf16 residual stream in d_out storage

  transpose_w<<<dim3(4, 8, 1), 256, 0, stream>>>(cp_w1, WT_cp1, 512, 256);
  transpose_w<<<dim3(4, 4, 1), 256, 0, stream>>>(cp_w2, WT_cp2, 256, 256);
  transpose_w<<<dim3(24, 4, 6), 256, 0, stream>>>(adaln_w, WT_all, 256, 1536);
  transpose_w<<<dim3(8, 4, 1), 256, 0, stream>>>(fa_w, WT_all + 9216L * 256, 256, 512);
  transpose_w<<<dim3(12, 4, 6), 256, 0, stream>>>(qkv_w, WT_qkv, 256, 768);
  transpose_w<<<dim3(4, 4, 6), 256, 0, stream>>>(op_w, WT_op, 256, 256);
  transpose_w<<<dim3(8, 4, 6), 256, 0, stream>>>(ffn_w1, WT_f1, 256, 512);
  transpose_w<<<dim3(4, 8, 6), 256, 0, stream>>>(ffn_w2, WT_f2, 512, 256);
  transpose_w<<<dim3(4, 4, 1), 256, 0, stream>>>(fp_w, WT_fp, 256, 256);
  concat_bias<<<38, 256, 0, stream>>>(adaln_b, fa_b, bias_all);

  te_table_kernel<<<21, 1024, 0, stream>>>(emb, te_w1, te_b1, te_w2, te_b2, te_tab);
  cond_mean_kernel<<<4096, 256, 0, stream>>>(backbone, cond);

  gemm_bt<1><<<dim3(2, 32), 256, 0, stream>>>(cond, WT_cp1, cp_b1, c1, nullptr, nullptr, 4096, 256, 512);
  gemm_bt<4><<<dim3(2, 32), 256, 0, stream>>>(c1, WT_cp2, cp_b2, mc, tvec, te_tab, 4096, 256, 256);
  // single GEMM over 6 adaLN layers + final adaLN: N = 9728 (2432 blocks)
  gemm_bt<0><<<dim3(76, 32), 256, 0, stream>>>(mc, WT_all, bias_all, modb6, nullptr, nullptr, 4096, 9728, 256);

  // layer-0 input LN (sh1/sc1)
  ln_mod<<<BSr / 4, 256, 0, stream>>>(x_t, modb6, 9728, 0, 256, hbuf);

  for (int l = 0; l < L; ++l) {
    const u16* mb = modb6 + (long)l * 1536;  // batch-major: row stride 9728
    gemm_bt<0><<<dim3(6, BSr / 128), 256, 0, stream>>>(hbuf, WT_qkv + (long)l * 768 * 256, qkv_b + l * 768,
                                                       qkvbuf, nullptr, nullptr, (int)BSr, 768, 256);
    attn_kernel<<<B * 2, 128, 0, stream>>>(qkvbuf, hbuf);
    // x = xin + g1*(attn_out @ Wop + b); h = LN(x)*(1+sc2)+sh2   (2 elems/block pipelined)
    if (l == 0)
      gemm_ln<256, true><<<BSr / 128, 256, 0, stream>>>(hbuf, WT_op, op_b, x_t, mb + 512, 9728,
                                                        mb + 768, mb + 1024, 9728, xbuf, hbuf);
    else
      gemm_ln<256, false><<<BSr / 128, 256, 0, stream>>>(hbuf, WT_op + (long)l * 256 * 256, op_b + l * 256,
                                                         xbuf, mb + 512, 9728, mb + 768, mb + 1024, 9728, xbuf, hbuf);
    // fused FFN1+FFN2 + residual + next-layer LN (2 elems per block, pipelined)
    const u16* nsh = (l < 5) ? (mb + 1536) : (modb6 + 9216);
    const u16* nsc = (l < 5) ? (mb + 1536 + 256) : (modb6 + 9216 + 256);
    ffn_fused<<<BSr / 128, 512, 0, stream>>>(hbuf, WT_f1 + (long)l * 512 * 256, ffn_b1 + l * 512,
                                             WT_f2 + (long)l * 256 * 512, ffn_b2 + l * 256,
                                             xbuf, mb + 1280, 9728, nsh, nsc, 9728, xbuf, hbuf);
  }
  gemm_bt<3><<<dim3(2, BSr / 128), 256, 0, stream>>>(hbuf, WT_fp, fp_b, d_out, nullptr, nullptr, (int)BSr, 256, 256);
}

// Round 19
// 6257.694 us; speedup vs baseline: 1.0429x; 1.0429x over previous
//
#include <hip/hip_runtime.h>

typedef unsigned short u16;
typedef float f32x4 __attribute__((ext_vector_type(4)));
typedef __bf16 bf16x8 __attribute__((ext_vector_type(8)));

__device__ __forceinline__ u16 f2b(float f) {
  unsigned u = __builtin_bit_cast(unsigned, f);
  u += 0x7FFF + ((u >> 16) & 1);
  return (u16)(u >> 16);
}

__device__ __forceinline__ float b2f(u16 v) {
  unsigned u = (unsigned)v << 16;
  return __builtin_bit_cast(float, u);
}

__device__ __forceinline__ f32x4 ld_bf4(const u16* p) {
  ushort4 v = *(const ushort4*)p;
  f32x4 r;
  r[0] = b2f(v.x); r[1] = b2f(v.y); r[2] = b2f(v.z); r[3] = b2f(v.w);
  return r;
}

// mish(x) = x * tanh(softplus(x)) = x * (e^2+2e)/(e^2+2e+2), e = exp(x)
__device__ __forceinline__ float mishf(float x) {
  float e = __expf(fminf(x, 20.f));
  float n = e * (e + 2.f);
  return x * __fdividef(n, n + 2.f);
}

__device__ __forceinline__ void gl_lds16(const void* g, void* l) {
  __builtin_amdgcn_global_load_lds((__attribute__((address_space(1))) void*)g,
                                   (__attribute__((address_space(3))) void*)l, 16, 0, 0);
}

__device__ __forceinline__ bf16x8 ldb8(const u16* p) {
  return __builtin_bit_cast(bf16x8, *(const uint4*)p);
}

// ---------------- weight transpose f32[K,N] -> bf16[N,K] ----------------
__global__ __launch_bounds__(256)
void transpose_w(const float* __restrict__ in, u16* __restrict__ out, int K, int N) {
  __shared__ float tl[64][65];
  const long zoff = (long)blockIdx.z * K * N;
  in += zoff; out += zoff;
  const int n0 = blockIdx.x * 64, k0 = blockIdx.y * 64;
  const int c = threadIdx.x & 63, r0 = threadIdx.x >> 6;
#pragma unroll
  for (int i = 0; i < 16; ++i) {
    int r = i * 4 + r0;
    tl[r][c] = in[(long)(k0 + r) * N + n0 + c];
  }
  __syncthreads();
#pragma unroll
  for (int i = 0; i < 16; ++i) {
    int r = i * 4 + r0;
    out[(long)(n0 + r) * K + k0 + c] = f2b(tl[c][r]);
  }
}

// ---------------- timestep-embedding MLP table (21 rows) ----------------
__global__ __launch_bounds__(1024)
void te_table_kernel(const float* __restrict__ emb, const float* __restrict__ w1,
                     const float* __restrict__ b1, const float* __restrict__ w2,
                     const float* __restrict__ b2, float* __restrict__ table) {
  __shared__ float te[256];
  __shared__ float h1[1024];
  __shared__ float red[1024];
  const int tt = blockIdx.x, tid = threadIdx.x;
  if (tid < 256) te[tid] = emb[tt * 256 + tid];
  __syncthreads();
  float a = b1[tid];
#pragma unroll 8
  for (int k = 0; k < 256; ++k) a += te[k] * w1[k * 1024 + tid];
  h1[tid] = mishf(a);
  __syncthreads();
  const int j = tid & 255, kq = tid >> 8;
  float a2 = 0.f;
#pragma unroll 8
  for (int k = kq * 256; k < kq * 256 + 256; ++k) a2 += h1[k] * w2[k * 256 + j];
  red[tid] = a2;
  __syncthreads();
  if (tid < 256)
    table[tt * 256 + tid] = b2[tid] + red[tid] + red[tid + 256] + red[tid + 512] + red[tid + 768];
}

// ---------------- cond = mean over S, written bf16 ----------------
__global__ __launch_bounds__(256)
void cond_mean_kernel(const float* __restrict__ bb, u16* __restrict__ cond) {
  const int b = blockIdx.x, tid = threadIdx.x;
  const float* p = bb + (long)b * 64 * 512;
  for (int d = tid; d < 512; d += 256) {
    float s = 0.f;
#pragma unroll
    for (int t = 0; t < 64; ++t) s += p[t * 512 + d];
    cond[b * 512 + d] = f2b(s * (1.f / 64.f));
  }
}

// ---------------- LayerNorm + adaLN modulate -> bf16 (layer-0 input; mod is bf16) ----------------
__global__ __launch_bounds__(256)
void ln_mod(const float* __restrict__ x, const u16* __restrict__ modb,
            int mstride, int shoff, int scoff, u16* __restrict__ out) {
  const int lane = threadIdx.x & 63;
  const long row = (long)blockIdx.x * 4 + (threadIdx.x >> 6);
  const float4 xv = *(const float4*)(x + row * 256 + lane * 4);
  float s1 = xv.x + xv.y + xv.z + xv.w;
  float s2 = xv.x * xv.x + xv.y * xv.y + xv.z * xv.z + xv.w * xv.w;
#pragma unroll
  for (int m = 1; m < 64; m <<= 1) { s1 += __shfl_xor(s1, m); s2 += __shfl_xor(s2, m); }
  const float mean = s1 * (1.f / 256.f);
  float var = s2 * (1.f / 256.f) - mean * mean;
  const float rstd = rsqrtf(fmaxf(var, 0.f) + 1e-5f);
  const long b = row >> 6;
  const f32x4 sc = ld_bf4(modb + b * mstride + scoff + lane * 4);
  const f32x4 sh = ld_bf4(modb + b * mstride + shoff + lane * 4);
  ushort4 o;
  o.x = f2b((xv.x - mean) * rstd * (1.f + sc[0]) + sh[0]);
  o.y = f2b((xv.y - mean) * rstd * (1.f + sc[1]) + sh[1]);
  o.z = f2b((xv.z - mean) * rstd * (1.f + sc[2]) + sh[2]);
  o.w = f2b((xv.w - mean) * rstd * (1.f + sc[3]) + sh[3]);
  *(ushort4*)(out + row * 256 + lane * 4) = o;
}

// ---------------- GEMM: C[M,N] = A[M,K](bf16) @ Bt[N,K]^T(bf16) + epilogue ----------------
// EPI 0: +bias -> bf16 | 1: mish(+bias) -> bf16 | 3: +bias -> f32
// EPI 4: mish(+bias + te_table[t[row]]) -> bf16
template <int EPI>
__global__ __launch_bounds__(256)
void gemm_bt(const u16* __restrict__ A, const u16* __restrict__ Bt,
             const float* __restrict__ bias, void* __restrict__ outp,
             const int* __restrict__ tvec, const float* __restrict__ tetab,
             int M, int N, int K) {
  __shared__ __align__(16) u16 As[2][128 * 64];
  __shared__ __align__(16) u16 Bs[2][128 * 64];
  const int tid = threadIdx.x;
  const int lane = tid & 63;
  const int wave = tid >> 6;
  const int wr = (wave >> 1) << 6;
  const int wc = (wave & 1) << 6;
  const long tm = (long)blockIdx.y * 128;
  const long tn = (long)blockIdx.x * 128;
  const u16* Ag = A + tm * K;
  const u16* Bg = Bt + tn * K;
  f32x4 acc[4][4] = {};
  const int kcb = lane >> 4;
  const int swz = lane & 7;
  const int NT = K >> 6;

  auto stage = [&](int t, int buf) {
    const int k0 = t << 6;
#pragma unroll
    for (int i = 0; i < 4; ++i) {
      int c = tid + (i << 8);
      int r = c >> 3;
      int sch = (c & 7) ^ (r & 7);
      gl_lds16(Ag + (long)r * K + k0 + (sch << 3), &As[buf][c << 3]);
    }
#pragma unroll
    for (int i = 0; i < 4; ++i) {
      int c = tid + (i << 8);
      int r = c >> 3;
      int sch = (c & 7) ^ (r & 7);
      gl_lds16(Bg + (long)r * K + k0 + (sch << 3), &Bs[buf][c << 3]);
    }
  };

  stage(0, 0);
  __syncthreads();
  int cur = 0;
  for (int t = 0; t < NT; ++t) {
    if (t + 1 < NT) stage(t + 1, cur ^ 1);
#pragma unroll
    for (int kt = 0; kt < 2; ++kt) {
      const int ko = ((kt * 4 + kcb) ^ swz) << 3;
      bf16x8 av[4], bv[4];
#pragma unroll
      for (int mt = 0; mt < 4; ++mt)
        av[mt] = ldb8(&As[cur][(wr + mt * 16 + (lane & 15)) * 64 + ko]);
#pragma unroll
      for (int nt = 0; nt < 4; ++nt)
        bv[nt] = ldb8(&Bs[cur][(wc + nt * 16 + (lane & 15)) * 64 + ko]);
#pragma unroll
      for (int mt = 0; mt < 4; ++mt)
#pragma unroll
        for (int nt = 0; nt < 4; ++nt)
          acc[mt][nt] = __builtin_amdgcn_mfma_f32_16x16x32_bf16(bv[nt], av[mt], acc[mt][nt], 0, 0, 0);
    }
    __syncthreads();
    cur ^= 1;
  }
  const int rl = lane & 15;
  const int c4 = (lane >> 4) << 2;
  f32x4 b4[4];
#pragma unroll
  for (int nt = 0; nt < 4; ++nt)
    b4[nt] = *(const f32x4*)(bias + (int)tn + wc + nt * 16 + c4);
#pragma unroll
  for (int mt = 0; mt < 4; ++mt) {
    const unsigned row = (unsigned)(tm + wr + mt * 16 + rl);
    const unsigned rb = row * (unsigned)N;
#pragma unroll
    for (int nt = 0; nt < 4; ++nt) {
      const unsigned col = (unsigned)tn + wc + nt * 16 + c4;
      f32x4 v = acc[mt][nt] + b4[nt];
      if constexpr (EPI == 0) {
        ushort4 o;
        o.x = f2b(v[0]); o.y = f2b(v[1]); o.z = f2b(v[2]); o.w = f2b(v[3]);
        *(ushort4*)((u16*)outp + rb + col) = o;
      } else if constexpr (EPI == 1) {
        ushort4 o;
        o.x = f2b(mishf(v[0])); o.y = f2b(mishf(v[1]));
        o.z = f2b(mishf(v[2])); o.w = f2b(mishf(v[3]));
        *(ushort4*)((u16*)outp + rb + col) = o;
      } else if constexpr (EPI == 3) {
        *(f32x4*)((float*)outp + rb + col) = v;
      } else {
        const f32x4 te = *(const f32x4*)(tetab + tvec[row] * 256 + col);
        ushort4 o;
        o.x = f2b(mishf(v[0] + te[0])); o.y = f2b(mishf(v[1] + te[1]));
        o.z = f2b(mishf(v[2] + te[2])); o.w = f2b(mishf(v[3] + te[3]));
        *(ushort4*)((u16*)outp + rb + col) = o;
      }
    }
  }
}

// ---------------- GEMM (N=256 full rows) + residual + LayerNorm + modulate ----------------
// (op-projection stage) 256 thr / 4 waves; block = 64 rows. Residual bf16; mods bf16.
template <int K, bool XF32>
__global__ __launch_bounds__(256)
void gemm_ln(const u16* __restrict__ A, const u16* __restrict__ Bt,
             const float* __restrict__ bias, const void* __restrict__ xin,
             const u16* __restrict__ gptr, int gstride,
             const u16* __restrict__ lnsh, const u16* __restrict__ lnsc, int lnstride,
             u16* __restrict__ xout, u16* __restrict__ hout) {
  __shared__ __align__(16) u16 As[2][64 * 64];
  __shared__ __align__(16) u16 Bs[2][256 * 64];
  const int tid = threadIdx.x, lane = tid & 63, wave = tid >> 6;
  const int wc = wave << 6;
  const long tm = (long)blockIdx.x * 64;
  const u16* Ag = A + tm * K;
  const int rl = lane & 15;
  const int c4 = (lane >> 4) << 2;
  const int swz = lane & 7;
  const int NT = K >> 6;

  auto stage = [&](int t, int buf) {
    const int k0 = t << 6;
#pragma unroll
    for (int i = 0; i < 2; ++i) {
      int c = tid + (i << 8);
      int r = c >> 3;
      int sch = (c & 7) ^ (r & 7);
      gl_lds16(Ag + (long)r * K + k0 + (sch << 3), &As[buf][c << 3]);
    }
#pragma unroll
    for (int i = 0; i < 8; ++i) {
      int c = tid + (i << 8);
      int r = c >> 3;
      int sch = (c & 7) ^ (r & 7);
      gl_lds16(Bt + (long)r * K + k0 + (sch << 3), &Bs[buf][c << 3]);
    }
  };

  stage(0, 0);
  __syncthreads();

  f32x4 acc[4][4] = {};
  int cur = 0;
  for (int t = 0; t < NT; ++t) {
    if (t + 1 < NT) stage(t + 1, cur ^ 1);
#pragma unroll
    for (int kt = 0; kt < 2; ++kt) {
      const int ko = ((kt * 4 + (lane >> 4)) ^ swz) << 3;
      bf16x8 av[4], bv[4];
#pragma unroll
      for (int mt = 0; mt < 4; ++mt)
        av[mt] = ldb8(&As[cur][(mt * 16 + rl) * 64 + ko]);
#pragma unroll
      for (int nt = 0; nt < 4; ++nt)
        bv[nt] = ldb8(&Bs[cur][(wc + nt * 16 + rl) * 64 + ko]);
#pragma unroll
      for (int mt = 0; mt < 4; ++mt)
#pragma unroll
        for (int nt = 0; nt < 4; ++nt)
          acc[mt][nt] = __builtin_amdgcn_mfma_f32_16x16x32_bf16(bv[nt], av[mt], acc[mt][nt], 0, 0, 0);
    }
    __syncthreads();
    cur ^= 1;
  }

  const long b = blockIdx.x;
  float s1[4] = {}, s2[4] = {};
#pragma unroll
  for (int nt = 0; nt < 4; ++nt) {
    const int col = wc + nt * 16 + c4;
    const f32x4 b4 = *(const f32x4*)(bias + col);
    const f32x4 g4 = ld_bf4(gptr + b * gstride + col);
#pragma unroll
    for (int mt = 0; mt < 4; ++mt) {
      const long row = tm + mt * 16 + rl;
      f32x4 x;
      if constexpr (XF32) x = *(const f32x4*)((const float*)xin + row * 256 + col);
      else x = ld_bf4((const u16*)xin + row * 256 + col);
      f32x4 xn = x + g4 * (acc[mt][nt] + b4);
      acc[mt][nt] = xn;
      s1[mt] += xn[0] + xn[1] + xn[2] + xn[3];
      s2[mt] += xn[0] * xn[0] + xn[1] * xn[1] + xn[2] * xn[2] + xn[3] * xn[3];
    }
  }
#pragma unroll
  for (int mt = 0; mt < 4; ++mt) {
    s1[mt] += __shfl_xor(s1[mt], 16); s1[mt] += __shfl_xor(s1[mt], 32);
    s2[mt] += __shfl_xor(s2[mt], 16); s2[mt] += __shfl_xor(s2[mt], 32);
  }
  float* st = (float*)&As[0][0];
  if (lane < 16) {
#pragma unroll
    for (int mt = 0; mt < 4; ++mt) {
      st[wave * 128 + mt * 16 + lane] = s1[mt];
      st[wave * 128 + 64 + mt * 16 + lane] = s2[mt];
    }
  }
  __syncthreads();
  float mean[4], rstd[4];
#pragma unroll
  for (int mt = 0; mt < 4; ++mt) {
    float a = 0.f, q = 0.f;
#pragma unroll
    for (int w2 = 0; w2 < 4; ++w2) {
      a += st[w2 * 128 + mt * 16 + rl];
      q += st[w2 * 128 + 64 + mt * 16 + rl];
    }
    mean[mt] = a * (1.f / 256.f);
    float var = q * (1.f / 256.f) - mean[mt] * mean[mt];
    rstd[mt] = rsqrtf(fmaxf(var, 0.f) + 1e-5f);
  }
#pragma unroll
  for (int nt = 0; nt < 4; ++nt) {
    const int col = wc + nt * 16 + c4;
    const f32x4 sc4 = ld_bf4(lnsc + b * lnstride + col);
    const f32x4 sh4 = ld_bf4(lnsh + b * lnstride + col);
#pragma unroll
    for (int mt = 0; mt < 4; ++mt) {
      const long row = tm + mt * 16 + rl;
      ushort4 xo;
      xo.x = f2b(acc[mt][nt][0]); xo.y = f2b(acc[mt][nt][1]);
      xo.z = f2b(acc[mt][nt][2]); xo.w = f2b(acc[mt][nt][3]);
      *(ushort4*)(xout + row * 256 + col) = xo;
      f32x4 h = (acc[mt][nt] - mean[mt]) * rstd[mt] * (1.f + sc4) + sh4;
      ushort4 o;
      o.x = f2b(h[0]); o.y = f2b(h[1]); o.z = f2b(h[2]); o.w = f2b(h[3]);
      *(ushort4*)(hout + row * 256 + col) = o;
    }
  }
}

// ---------------- fused FFN: x=x+g2*(mish(xln@W1^T+b1)@W2^T+b2); h=LN(x)*(1+sc)+sh ----------------
// Block processes TWO batch elems, software-pipelined: elem e+1's Ax stage issues during
// elem e's phase B (Ax dead after phase A); elem e+1's W1-tile0 stage issues in e's
// phase-B t=7 slot. R11-proven inner structure per elem. LDS 160KB (1 block/CU).
__global__ __launch_bounds__(512)
void ffn_fused(const u16* __restrict__ xln, const u16* __restrict__ W1t,
               const float* __restrict__ b1, const u16* __restrict__ W2t,
               const float* __restrict__ b2, const u16* __restrict__ xres,
               const u16* __restrict__ gptr, int gstride,
               const u16* __restrict__ lnsh, const u16* __restrict__ lnsc, int lnstride,
               u16* __restrict__ xout, u16* __restrict__ hout) {
  __shared__ __align__(16) u16 Ax[64 * 256];
  __shared__ __align__(16) u16 Ws[2][256 * 64];
  __shared__ __align__(16) u16 H1[64 * 512];
  const int tid = threadIdx.x, lane = tid & 63, wave = tid >> 6;
  const long b0 = (long)blockIdx.x * 2;
  const int rl = lane & 15;
  const int c4 = (lane >> 4) << 2;
  const int kq = lane >> 4;

  auto stageAx = [&](long b) {
    const u16* src = xln + b * (64 * 256);
#pragma unroll
    for (int i = 0; i < 4; ++i) {
      int c = tid + (i << 9);
      int r = c >> 5, cc = c & 31;
      int sch = (cc & ~7) | ((cc & 7) ^ (r & 7));
      gl_lds16(src + r * 256 + (sch << 3), &Ax[c << 3]);
    }
  };
  auto stageW = [&](const u16* Wsrc, int Kw, int R0, int k0, int buf) {
#pragma unroll
    for (int i = 0; i < 4; ++i) {
      int c = tid + (i << 9);
      int r = c >> 3;
      int sch = (c & 7) ^ (r & 7);
      gl_lds16(Wsrc + (long)(R0 + r) * Kw + k0 + (sch << 3), &Ws[buf][c << 3]);
    }
  };

  stageAx(b0);
  stageW(W1t, 256, 0, 0, 0);
  __syncthreads();
  int cur = 0;

  for (int e = 0; e < 2; ++e) {
    const long b = b0 + e;
    // ---- phase A: h1 = mish(xln @ W1t^T + b1), two 256-col halves ----
    for (int nh = 0; nh < 2; ++nh) {
      f32x4 acc[4][2] = {};
      for (int t = 0; t < 4; ++t) {
        int s = nh * 4 + t;
        if (s < 7) stageW(W1t, 256, ((s + 1) >> 2) * 256, ((s + 1) & 3) * 64, cur ^ 1);
        else stageW(W2t, 512, 0, 0, cur ^ 1);  // prefetch phase-B tile 0
#pragma unroll
        for (int kt = 0; kt < 2; ++kt) {
          bf16x8 av[4], bv[2];
#pragma unroll
          for (int mt = 0; mt < 4; ++mt) {
            int r = mt * 16 + rl;
            int kc = t * 8 + kt * 4 + kq;
            int slot = (kc & ~7) | ((kc & 7) ^ (r & 7));
            av[mt] = ldb8(&Ax[r * 256 + (slot << 3)]);
          }
#pragma unroll
          for (int nf = 0; nf < 2; ++nf) {
            int wr_ = wave * 32 + nf * 16 + rl;
            int slot = (kt * 4 + kq) ^ (wr_ & 7);
            bv[nf] = ldb8(&Ws[cur][wr_ * 64 + (slot << 3)]);
          }
#pragma unroll
          for (int mt = 0; mt < 4; ++mt)
#pragma unroll
            for (int nf = 0; nf < 2; ++nf)
              acc[mt][nf] = __builtin_amdgcn_mfma_f32_16x16x32_bf16(bv[nf], av[mt], acc[mt][nf], 0, 0, 0);
        }
        __syncthreads();
        cur ^= 1;
      }
      // epilogue A: mish -> H1 (swizzled ds_write)
#pragma unroll
      for (int nf = 0; nf < 2; ++nf) {
        const int col = nh * 256 + wave * 32 + nf * 16 + c4;
        const f32x4 bb = *(const f32x4*)(b1 + col);
        const int c8 = col >> 3;
        const int sub = (col & 7) << 1;
#pragma unroll
        for (int mt = 0; mt < 4; ++mt) {
          const int r = mt * 16 + rl;
          f32x4 v = acc[mt][nf] + bb;
          ushort4 o;
          o.x = f2b(mishf(v[0])); o.y = f2b(mishf(v[1]));
          o.z = f2b(mishf(v[2])); o.w = f2b(mishf(v[3]));
          int slot = (c8 & ~7) | ((c8 & 7) ^ (r & 7));
          *(ushort4*)((char*)H1 + r * 1024 + (slot << 4) + sub) = o;
        }
      }
    }
    __syncthreads();  // H1 visible; W2 tile 0 staged; all Ax reads complete

    // ---- phase B: out = h1 @ W2t^T + b2; residual + LN ----
    f32x4 acc[4][2] = {};
    for (int t = 0; t < 8; ++t) {
      if (t < 7) stageW(W2t, 512, 0, (t + 1) * 64, cur ^ 1);
      else if (e == 0) stageW(W1t, 256, 0, 0, cur ^ 1);  // next elem's W1 tile 0
      if (t == 0 && e == 0) stageAx(b0 + 1);             // next elem's x (Ax dead)
#pragma unroll
      for (int kt = 0; kt < 2; ++kt) {
        bf16x8 av[4], bv[2];
#pragma unroll
        for (int mt = 0; mt < 4; ++mt) {
          int r = mt * 16 + rl;
          int kc = t * 8 + kt * 4 + kq;
          int slot = (kc & ~7) | ((kc & 7) ^ (r & 7));
          av[mt] = ldb8((const u16*)((const char*)H1 + r * 1024 + (slot << 4)));
        }
#pragma unroll
        for (int nf = 0; nf < 2; ++nf) {
          int wr_ = wave * 32 + nf * 16 + rl;
          int slot = (kt * 4 + kq) ^ (wr_ & 7);
          bv[nf] = ldb8(&Ws[cur][wr_ * 64 + (slot << 3)]);
        }
#pragma unroll
        for (int mt = 0; mt < 4; ++mt)
#pragma unroll
          for (int nf = 0; nf < 2; ++nf)
            acc[mt][nf] = __builtin_amdgcn_mfma_f32_16x16x32_bf16(bv[nf], av[mt], acc[mt][nf], 0, 0, 0);
      }
      __syncthreads();
      cur ^= 1;
    }
    // residual + row stats (wave's 32-col strip); stats scratch in H1 (dead after phase B)
    float s1[4] = {}, s2[4] = {};
#pragma unroll
    for (int nf = 0; nf < 2; ++nf) {
      const int col = wave * 32 + nf * 16 + c4;
      const f32x4 bb = *(const f32x4*)(b2 + col);
      const f32x4 g4 = ld_bf4(gptr + b * gstride + col);
#pragma unroll
      for (int mt = 0; mt < 4; ++mt) {
        const long row = b * 64 + mt * 16 + rl;
        f32x4 x = ld_bf4(xres + row * 256 + col);
        f32x4 xn = x + g4 * (acc[mt][nf] + bb);
        acc[mt][nf] = xn;
        s1[mt] += xn[0] + xn[1] + xn[2] + xn[3];
        s2[mt] += xn[0] * xn[0] + xn[1] * xn[1] + xn[2] * xn[2] + xn[3] * xn[3];
      }
    }
#pragma unroll
    for (int mt = 0; mt < 4; ++mt) {
      s1[mt] += __shfl_xor(s1[mt], 16); s1[mt] += __shfl_xor(s1[mt], 32);
      s2[mt] += __shfl_xor(s2[mt], 16); s2[mt] += __shfl_xor(s2[mt], 32);
    }
    float* st = (float*)&H1[0];
    if (lane < 16) {
#pragma unroll
      for (int mt = 0; mt < 4; ++mt) {
        st[wave * 128 + mt * 16 + lane] = s1[mt];
        st[wave * 128 + 64 + mt * 16 + lane] = s2[mt];
      }
    }
    __syncthreads();
    float mean[4], rstd[4];
#pragma unroll
    for (int mt = 0; mt < 4; ++mt) {
      float a = 0.f, q = 0.f;
#pragma unroll
      for (int w2 = 0; w2 < 8; ++w2) {
        a += st[w2 * 128 + mt * 16 + rl];
        q += st[w2 * 128 + 64 + mt * 16 + rl];
      }
      mean[mt] = a * (1.f / 256.f);
      float var = q * (1.f / 256.f) - mean[mt] * mean[mt];
      rstd[mt] = rsqrtf(fmaxf(var, 0.f) + 1e-5f);
    }
#pragma unroll
    for (int nf = 0; nf < 2; ++nf) {
      const int col = wave * 32 + nf * 16 + c4;
      const f32x4 sc4 = ld_bf4(lnsc + b * lnstride + col);
      const f32x4 sh4 = ld_bf4(lnsh + b * lnstride + col);
#pragma unroll
      for (int mt = 0; mt < 4; ++mt) {
        const long row = b * 64 + mt * 16 + rl;
        ushort4 xo;
        xo.x = f2b(acc[mt][nf][0]); xo.y = f2b(acc[mt][nf][1]);
        xo.z = f2b(acc[mt][nf][2]); xo.w = f2b(acc[mt][nf][3]);
        *(ushort4*)(xout + row * 256 + col) = xo;
        f32x4 h = (acc[mt][nf] - mean[mt]) * rstd[mt] * (1.f + sc4) + sh4;
        ushort4 o;
        o.x = f2b(h[0]); o.y = f2b(h[1]); o.z = f2b(h[2]); o.w = f2b(h[3]);
        *(ushort4*)(hout + row * 256 + col) = o;
      }
    }
    __syncthreads();  // stats reads done before next elem's epilogue-A overwrites H1
  }
}

// ---------------- fused attention: per (b, head-pair) block, wave=head ----------------
__global__ __launch_bounds__(128)
void attn_kernel(const u16* __restrict__ qkv, u16* __restrict__ out) {
  __shared__ __align__(16) u16 vt_s[2][64 * 72];
  __shared__ __align__(16) u16 p_s[2][64 * 72];
  const int lane = threadIdx.x & 63;
  const int wave = threadIdx.x >> 6;
  const long b = blockIdx.x >> 1;
  const int h = ((blockIdx.x & 1) << 1) | wave;
  u16* vt = vt_s[wave];
  u16* pl = p_s[wave];
  const u16* base = qkv + b * (64 * 768);
#pragma unroll
  for (int it = 0; it < 8; ++it) {
    int chunk = it * 64 + lane;
    int t = chunk >> 3, dhb = (chunk & 7) << 3;
    union { uint4 u; u16 s[8]; } uv;
    uv.u = *(const uint4*)(base + t * 768 + 512 + h * 64 + dhb);
#pragma unroll
    for (int j = 0; j < 8; ++j) vt[(dhb + j) * 72 + t] = uv.s[j];
  }
  const u16* qb = base + h * 64;
  const u16* kb = base + 256 + h * 64;
  f32x4 sacc[4][4] = {};
#pragma unroll
  for (int kt = 0; kt < 2; ++kt) {
    bf16x8 qa[4], kv[4];
#pragma unroll
    for (int mt = 0; mt < 4; ++mt)
      qa[mt] = ldb8(qb + ((lane & 15) + mt * 16) * 768 + kt * 32 + ((lane >> 4) << 3));
#pragma unroll
    for (int nt = 0; nt < 4; ++nt)
      kv[nt] = ldb8(kb + ((lane & 15) + nt * 16) * 768 + kt * 32 + ((lane >> 4) << 3));
#pragma unroll
    for (int mt = 0; mt < 4; ++mt)
#pragma unroll
      for (int nt = 0; nt < 4; ++nt)
        sacc[mt][nt] = __builtin_amdgcn_mfma_f32_16x16x32_bf16(qa[mt], kv[nt], sacc[mt][nt], 0, 0, 0);
  }
  const float scale = 0.125f;
#pragma unroll
  for (int mt = 0; mt < 4; ++mt) {
#pragma unroll
    for (int r = 0; r < 4; ++r) {
      float mx = fmaxf(fmaxf(sacc[mt][0][r], sacc[mt][1][r]), fmaxf(sacc[mt][2][r], sacc[mt][3][r]));
#pragma unroll
      for (int m = 1; m <= 8; m <<= 1) mx = fmaxf(mx, __shfl_xor(mx, m));
      float p[4];
      float sum = 0.f;
#pragma unroll
      for (int nt = 0; nt < 4; ++nt) { p[nt] = __expf((sacc[mt][nt][r] - mx) * scale); sum += p[nt]; }
#pragma unroll
      for (int m = 1; m <= 8; m <<= 1) sum += __shfl_xor(sum, m);
      const float rinv = 1.f / sum;
      const int s = mt * 16 + ((lane >> 4) << 2) + r;
#pragma unroll
      for (int nt = 0; nt < 4; ++nt) pl[s * 72 + nt * 16 + (lane & 15)] = f2b(p[nt] * rinv);
    }
  }
  __syncthreads();
  f32x4 oacc[4][4] = {};
#pragma unroll
  for (int kt = 0; kt < 2; ++kt) {
    bf16x8 pa[4], vv[4];
#pragma unroll
    for (int mt = 0; mt < 4; ++mt)
      pa[mt] = ldb8(pl + ((lane & 15) + mt * 16) * 72 + kt * 32 + ((lane >> 4) << 3));
#pragma unroll
    for (int nt = 0; nt < 4; ++nt)
      vv[nt] = ldb8(vt + ((lane & 15) + nt * 16) * 72 + kt * 32 + ((lane >> 4) << 3));
#pragma unroll
    for (int mt = 0; mt < 4; ++mt)
#pragma unroll
      for (int nt = 0; nt < 4; ++nt)
        oacc[mt][nt] = __builtin_amdgcn_mfma_f32_16x16x32_bf16(vv[nt], pa[mt], oacc[mt][nt], 0, 0, 0);
  }
  u16* ob = out + b * (64 * 256) + h * 64;
#pragma unroll
  for (int mt = 0; mt < 4; ++mt)
#pragma unroll
    for (int nt = 0; nt < 4; ++nt) {
      const int s = mt * 16 + (lane & 15);
      const int d4 = nt * 16 + ((lane >> 4) << 2);
      ushort4 o;
      o.x = f2b(oacc[mt][nt][0]); o.y = f2b(oacc[mt][nt][1]);
      o.z = f2b(oacc[mt][nt][2]); o.w = f2b(oacc[mt][nt][3]);
      *(ushort4*)(ob + s * 256 + d4) = o;
    }
}

extern "C" void kernel_launch(void* const* d_in, const int* in_sizes, int n_in,
                              void* d_out, int out_size, void* d_ws, size_t ws_size,
                              hipStream_t stream) {
  (void)in_sizes; (void)n_in; (void)out_size; (void)ws_size;
  const int B = 4096, L = 6;
  const long BSr = (long)B * 64;

  const float* x_t = (const float*)d_in[0];
  const int* tvec = (const int*)d_in[1];
  const float* backbone = (const float*)d_in[2];
  const float* emb = (const float*)d_in[3];
  const float* te_w1 = (const float*)d_in[4];
  const float* te_b1 = (const float*)d_in[5];
  const float* te_w2 = (const float*)d_in[6];
  const float* te_b2 = (const float*)d_in[7];
  const float* cp_w1 = (const float*)d_in[8];
  const float* cp_b1 = (const float*)d_in[9];
  const float* cp_w2 = (const float*)d_in[10];
  const float* cp_b2 = (const float*)d_in[11];
  const float* adaln_w = (const float*)d_in[12];
  const float* adaln_b = (const float*)d_in[13];
  const float* qkv_w = (const float*)d_in[14];
  const float* qkv_b = (const float*)d_in[15];
  const float* op_w = (const float*)d_in[16];
  const float* op_b = (const float*)d_in[17];
  const float* ffn_w1 = (const float*)d_in[18];
  const float* ffn_b1 = (const float*)d_in[19];
  const float* ffn_w2 = (const float*)d_in[20];
  const float* ffn_b2 = (const float*)d_in[21];
  const float* fa_w = (const float*)d_in[22];
  const float* fa_b = (const float*)d_in[23];
  const float* fp_w = (const float*)d_in[24];
  const float* fp_b = (const float*)d_in[25];

  char* w = (char*)d_ws;
  auto alloc = [&](size_t bytes) { char* p = w; w += (bytes + 255) & ~(size_t)255; return p; };
  u16* WT_cp1 = (u16*)alloc(256L * 512 * 2);
  u16* WT_cp2 = (u16*)alloc(256L * 256 * 2);
  u16* WT_adaln = (u16*)alloc(6L * 1536 * 256 * 2);  // = [9216][256] B^T
  u16* WT_qkv = (u16*)alloc(6L * 768 * 256 * 2);
  u16* WT_op = (u16*)alloc(6L * 256 * 256 * 2);
  u16* WT_f1 = (u16*)alloc(6L * 512 * 256 * 2);
  u16* WT_f2 = (u16*)alloc(6L * 256 * 512 * 2);
  u16* WT_fa = (u16*)alloc(512L * 256 * 2);
  u16* WT_fp = (u16*)alloc(256L * 256 * 2);
  float* te_tab = (float*)alloc(21L * 256 * 4);
  u16* cond = (u16*)alloc(4096L * 512 * 2);
  u16* c1 = (u16*)alloc(4096L * 256 * 2);
  u16* mc = (u16*)alloc(4096L * 256 * 2);
  u16* modb6 = (u16*)alloc(4096L * 9216 * 2);  // batch-major [4096][6*1536]
  u16* famod = (u16*)alloc(4096L * 512 * 2);
  u16* hbuf = (u16*)alloc(BSr * 256 * 2);
  u16* qkvbuf = (u16*)alloc(BSr * 768 * 2);
  u16* xbuf = (u16*)d_out;  // bf16 residual stream in d_out storage

  transpose_w<<<dim3(4, 8, 1), 256, 0, stream>>>(cp_w1, WT_cp1, 512, 256);
  transpose_w<<<dim3(4, 4, 1), 256, 0, stream>>>(cp_w2, WT_cp2, 256, 256);
  transpose_w<<<dim3(24, 4, 6), 256, 0, stream>>>(adaln_w, WT_adaln, 256, 1536);
  transpose_w<<<dim3(12, 4, 6), 256, 0, stream>>>(qkv_w, WT_qkv, 256, 768);
  transpose_w<<<dim3(4, 4, 6), 256, 0, stream>>>(op_w, WT_op, 256, 256);
  transpose_w<<<dim3(8, 4, 6), 256, 0, stream>>>(ffn_w1, WT_f1, 256, 512);
  transpose_w<<<dim3(4, 8, 6), 256, 0, stream>>>(ffn_w2, WT_f2, 512, 256);
  transpose_w<<<dim3(8, 4, 1), 256, 0, stream>>>(fa_w, WT_fa, 256, 512);
  transpose_w<<<dim3(4, 4, 1), 256, 0, stream>>>(fp_w, WT_fp, 256, 256);

  te_table_kernel<<<21, 1024, 0, stream>>>(emb, te_w1, te_b1, te_w2, te_b2, te_tab);
  cond_mean_kernel<<<4096, 256, 0, stream>>>(backbone, cond);

  gemm_bt<1><<<dim3(2, 32), 256, 0, stream>>>(cond, WT_cp1, cp_b1, c1, nullptr, nullptr, 4096, 256, 512);
  gemm_bt<4><<<dim3(2, 32), 256, 0, stream>>>(c1, WT_cp2, cp_b2, mc, tvec, te_tab, 4096, 256, 256);
  gemm_bt<0><<<dim3(4, 32), 256, 0, stream>>>(mc, WT_fa, fa_b, famod, nullptr, nullptr, 4096, 512, 256);
  // single adaLN GEMM over all 6 layers: N = 6*1536 = 9216 (2304 blocks)
  gemm_bt<0><<<dim3(72, 32), 256, 0, stream>>>(mc, WT_adaln, adaln_b, modb6, nullptr, nullptr, 4096, 9216, 256);

  // layer-0 input LN (sh1/sc1)
  ln_mod<<<BSr / 4, 256, 0, stream>>>(x_t, modb6, 9216, 0, 256, hbuf);

  for (int l = 0; l < L; ++l) {
    const u16* mb = modb6 + (long)l * 1536;  // batch-major: row stride 9216
    gemm_bt<0><<<dim3(6, BSr / 128), 256, 0, stream>>>(hbuf, WT_qkv + (long)l * 768 * 256, qkv_b + l * 768,
                                                       qkvbuf, nullptr, nullptr, (int)BSr, 768, 256);
    attn_kernel<<<B * 2, 128, 0, stream>>>(qkvbuf, hbuf);
    // x = xin + g1*(attn_out @ Wop + b); h = LN(x)*(1+sc2)+sh2
    if (l == 0)
      gemm_ln<256, true><<<BSr / 64, 256, 0, stream>>>(hbuf, WT_op, op_b, x_t, mb + 512, 9216,
                                                       mb + 768, mb + 1024, 9216, xbuf, hbuf);
    else
      gemm_ln<256, false><<<BSr / 64, 256, 0, stream>>>(hbuf, WT_op + (long)l * 256 * 256, op_b + l * 256,
                                                        xbuf, mb + 512, 9216, mb + 768, mb + 1024, 9216, xbuf, hbuf);
    // fused FFN1+FFN2 + residual + next-layer LN (2 elems per block, pipelined)
    const u16* nsh = (l < 5) ? (mb + 1536) : famod;
    const u16* nsc = (l < 5) ? (mb + 1536 + 256) : (famod + 256);
    const int nstride = (l < 5) ? 9216 : 512;
    ffn_fused<<<BSr / 128, 512, 0, stream>>>(hbuf, WT_f1 + (long)l * 512 * 256, ffn_b1 + l * 512,
                                             WT_f2 + (long)l * 256 * 512, ffn_b2 + l * 256,
                                             xbuf, mb + 1280, 9216, nsh, nsc, nstride, xbuf, hbuf);
  }
  gemm_bt<3><<<dim3(2, BSr / 128), 256, 0, stream>>>(hbuf, WT_fp, fp_b, d_out, nullptr, nullptr, (int)BSr, 256, 256);
}

// Round 20
// 6240.073 us; speedup vs baseline: 1.0458x; 1.0028x over previous
//
#include <hip/hip_runtime.h>

typedef unsigned short u16;
typedef float f32x4 __attribute__((ext_vector_type(4)));
typedef __bf16 bf16x8 __attribute__((ext_vector_type(8)));

__device__ __forceinline__ u16 f2b(float f) {
  unsigned u = __builtin_bit_cast(unsigned, f);
  u += 0x7FFF + ((u >> 16) & 1);
  return (u16)(u >> 16);
}

__device__ __forceinline__ float b2f(u16 v) {
  unsigned u = (unsigned)v << 16;
  return __builtin_bit_cast(float, u);
}

__device__ __forceinline__ f32x4 ld_bf4(const u16* p) {
  ushort4 v = *(const ushort4*)p;
  f32x4 r;
  r[0] = b2f(v.x); r[1] = b2f(v.y); r[2] = b2f(v.z); r[3] = b2f(v.w);
  return r;
}

// mish(x) = x * tanh(softplus(x)) = x * (e^2+2e)/(e^2+2e+2), e = exp(x)
__device__ __forceinline__ float mishf(float x) {
  float e = __expf(fminf(x, 20.f));
  float n = e * (e + 2.f);
  return x * __fdividef(n, n + 2.f);
}

__device__ __forceinline__ void gl_lds16(const void* g, void* l) {
  __builtin_amdgcn_global_load_lds((__attribute__((address_space(1))) void*)g,
                                   (__attribute__((address_space(3))) void*)l, 16, 0, 0);
}

__device__ __forceinline__ bf16x8 ldb8(const u16* p) {
  return __builtin_bit_cast(bf16x8, *(const uint4*)p);
}

// ---------------- weight transpose f32[K,N] -> bf16[N,K] ----------------
__global__ __launch_bounds__(256)
void transpose_w(const float* __restrict__ in, u16* __restrict__ out, int K, int N) {
  __shared__ float tl[64][65];
  const long zoff = (long)blockIdx.z * K * N;
  in += zoff; out += zoff;
  const int n0 = blockIdx.x * 64, k0 = blockIdx.y * 64;
  const int c = threadIdx.x & 63, r0 = threadIdx.x >> 6;
#pragma unroll
  for (int i = 0; i < 16; ++i) {
    int r = i * 4 + r0;
    tl[r][c] = in[(long)(k0 + r) * N + n0 + c];
  }
  __syncthreads();
#pragma unroll
  for (int i = 0; i < 16; ++i) {
    int r = i * 4 + r0;
    out[(long)(n0 + r) * K + k0 + c] = f2b(tl[c][r]);
  }
}

// ---------------- timestep-embedding MLP table (21 rows) ----------------
__global__ __launch_bounds__(1024)
void te_table_kernel(const float* __restrict__ emb, const float* __restrict__ w1,
                     const float* __restrict__ b1, const float* __restrict__ w2,
                     const float* __restrict__ b2, float* __restrict__ table) {
  __shared__ float te[256];
  __shared__ float h1[1024];
  __shared__ float red[1024];
  const int tt = blockIdx.x, tid = threadIdx.x;
  if (tid < 256) te[tid] = emb[tt * 256 + tid];
  __syncthreads();
  float a = b1[tid];
#pragma unroll 8
  for (int k = 0; k < 256; ++k) a += te[k] * w1[k * 1024 + tid];
  h1[tid] = mishf(a);
  __syncthreads();
  const int j = tid & 255, kq = tid >> 8;
  float a2 = 0.f;
#pragma unroll 8
  for (int k = kq * 256; k < kq * 256 + 256; ++k) a2 += h1[k] * w2[k * 256 + j];
  red[tid] = a2;
  __syncthreads();
  if (tid < 256)
    table[tt * 256 + tid] = b2[tid] + red[tid] + red[tid + 256] + red[tid + 512] + red[tid + 768];
}

// ---------------- cond = mean over S, written bf16 ----------------
__global__ __launch_bounds__(256)
void cond_mean_kernel(const float* __restrict__ bb, u16* __restrict__ cond) {
  const int b = blockIdx.x, tid = threadIdx.x;
  const float* p = bb + (long)b * 64 * 512;
  for (int d = tid; d < 512; d += 256) {
    float s = 0.f;
#pragma unroll
    for (int t = 0; t < 64; ++t) s += p[t * 512 + d];
    cond[b * 512 + d] = f2b(s * (1.f / 64.f));
  }
}

// ---------------- LayerNorm + adaLN modulate -> bf16 (layer-0 input; mod is bf16) ----------------
__global__ __launch_bounds__(256)
void ln_mod(const float* __restrict__ x, const u16* __restrict__ modb,
            int mstride, int shoff, int scoff, u16* __restrict__ out) {
  const int lane = threadIdx.x & 63;
  const long row = (long)blockIdx.x * 4 + (threadIdx.x >> 6);
  const float4 xv = *(const float4*)(x + row * 256 + lane * 4);
  float s1 = xv.x + xv.y + xv.z + xv.w;
  float s2 = xv.x * xv.x + xv.y * xv.y + xv.z * xv.z + xv.w * xv.w;
#pragma unroll
  for (int m = 1; m < 64; m <<= 1) { s1 += __shfl_xor(s1, m); s2 += __shfl_xor(s2, m); }
  const float mean = s1 * (1.f / 256.f);
  float var = s2 * (1.f / 256.f) - mean * mean;
  const float rstd = rsqrtf(fmaxf(var, 0.f) + 1e-5f);
  const long b = row >> 6;
  const f32x4 sc = ld_bf4(modb + b * mstride + scoff + lane * 4);
  const f32x4 sh = ld_bf4(modb + b * mstride + shoff + lane * 4);
  ushort4 o;
  o.x = f2b((xv.x - mean) * rstd * (1.f + sc[0]) + sh[0]);
  o.y = f2b((xv.y - mean) * rstd * (1.f + sc[1]) + sh[1]);
  o.z = f2b((xv.z - mean) * rstd * (1.f + sc[2]) + sh[2]);
  o.w = f2b((xv.w - mean) * rstd * (1.f + sc[3]) + sh[3]);
  *(ushort4*)(out + row * 256 + lane * 4) = o;
}

// ---------------- GEMM: C[M,N] = A[M,K](bf16) @ Bt[N,K]^T(bf16) + epilogue ----------------
// EPI 0: +bias -> bf16 | 1: mish(+bias) -> bf16 | 3: +bias -> f32
// EPI 4: mish(+bias + te_table[t[row]]) -> bf16
template <int EPI>
__global__ __launch_bounds__(256)
void gemm_bt(const u16* __restrict__ A, const u16* __restrict__ Bt,
             const float* __restrict__ bias, void* __restrict__ outp,
             const int* __restrict__ tvec, const float* __restrict__ tetab,
             int M, int N, int K) {
  __shared__ __align__(16) u16 As[2][128 * 64];
  __shared__ __align__(16) u16 Bs[2][128 * 64];
  const int tid = threadIdx.x;
  const int lane = tid & 63;
  const int wave = tid >> 6;
  const int wr = (wave >> 1) << 6;
  const int wc = (wave & 1) << 6;
  const long tm = (long)blockIdx.y * 128;
  const long tn = (long)blockIdx.x * 128;
  const u16* Ag = A + tm * K;
  const u16* Bg = Bt + tn * K;
  f32x4 acc[4][4] = {};
  const int kcb = lane >> 4;
  const int swz = lane & 7;
  const int NT = K >> 6;

  auto stage = [&](int t, int buf) {
    const int k0 = t << 6;
#pragma unroll
    for (int i = 0; i < 4; ++i) {
      int c = tid + (i << 8);
      int r = c >> 3;
      int sch = (c & 7) ^ (r & 7);
      gl_lds16(Ag + (long)r * K + k0 + (sch << 3), &As[buf][c << 3]);
    }
#pragma unroll
    for (int i = 0; i < 4; ++i) {
      int c = tid + (i << 8);
      int r = c >> 3;
      int sch = (c & 7) ^ (r & 7);
      gl_lds16(Bg + (long)r * K + k0 + (sch << 3), &Bs[buf][c << 3]);
    }
  };

  stage(0, 0);
  __syncthreads();
  int cur = 0;
  for (int t = 0; t < NT; ++t) {
    if (t + 1 < NT) stage(t + 1, cur ^ 1);
#pragma unroll
    for (int kt = 0; kt < 2; ++kt) {
      const int ko = ((kt * 4 + kcb) ^ swz) << 3;
      bf16x8 av[4], bv[4];
#pragma unroll
      for (int mt = 0; mt < 4; ++mt)
        av[mt] = ldb8(&As[cur][(wr + mt * 16 + (lane & 15)) * 64 + ko]);
#pragma unroll
      for (int nt = 0; nt < 4; ++nt)
        bv[nt] = ldb8(&Bs[cur][(wc + nt * 16 + (lane & 15)) * 64 + ko]);
#pragma unroll
      for (int mt = 0; mt < 4; ++mt)
#pragma unroll
        for (int nt = 0; nt < 4; ++nt)
          acc[mt][nt] = __builtin_amdgcn_mfma_f32_16x16x32_bf16(bv[nt], av[mt], acc[mt][nt], 0, 0, 0);
    }
    __syncthreads();
    cur ^= 1;
  }
  const int rl = lane & 15;
  const int c4 = (lane >> 4) << 2;
  f32x4 b4[4];
#pragma unroll
  for (int nt = 0; nt < 4; ++nt)
    b4[nt] = *(const f32x4*)(bias + (int)tn + wc + nt * 16 + c4);
#pragma unroll
  for (int mt = 0; mt < 4; ++mt) {
    const unsigned row = (unsigned)(tm + wr + mt * 16 + rl);
    const unsigned rb = row * (unsigned)N;
#pragma unroll
    for (int nt = 0; nt < 4; ++nt) {
      const unsigned col = (unsigned)tn + wc + nt * 16 + c4;
      f32x4 v = acc[mt][nt] + b4[nt];
      if constexpr (EPI == 0) {
        ushort4 o;
        o.x = f2b(v[0]); o.y = f2b(v[1]); o.z = f2b(v[2]); o.w = f2b(v[3]);
        *(ushort4*)((u16*)outp + rb + col) = o;
      } else if constexpr (EPI == 1) {
        ushort4 o;
        o.x = f2b(mishf(v[0])); o.y = f2b(mishf(v[1]));
        o.z = f2b(mishf(v[2])); o.w = f2b(mishf(v[3]));
        *(ushort4*)((u16*)outp + rb + col) = o;
      } else if constexpr (EPI == 3) {
        *(f32x4*)((float*)outp + rb + col) = v;
      } else {
        const f32x4 te = *(const f32x4*)(tetab + tvec[row] * 256 + col);
        ushort4 o;
        o.x = f2b(mishf(v[0] + te[0])); o.y = f2b(mishf(v[1] + te[1]));
        o.z = f2b(mishf(v[2] + te[2])); o.w = f2b(mishf(v[3] + te[3]));
        *(ushort4*)((u16*)outp + rb + col) = o;
      }
    }
  }
}

// ---------------- GEMM (N=256 full rows) + residual + LayerNorm + modulate ----------------
// (op-projection stage) 256 thr / 4 waves; block = 64 rows. Residual bf16; mods bf16.
template <int K, bool XF32>
__global__ __launch_bounds__(256)
void gemm_ln(const u16* __restrict__ A, const u16* __restrict__ Bt,
             const float* __restrict__ bias, const void* __restrict__ xin,
             const u16* __restrict__ gptr, int gstride,
             const u16* __restrict__ lnsh, const u16* __restrict__ lnsc, int lnstride,
             u16* __restrict__ xout, u16* __restrict__ hout) {
  __shared__ __align__(16) u16 As[2][64 * 64];
  __shared__ __align__(16) u16 Bs[2][256 * 64];
  const int tid = threadIdx.x, lane = tid & 63, wave = tid >> 6;
  const int wc = wave << 6;
  const long tm = (long)blockIdx.x * 64;
  const u16* Ag = A + tm * K;
  const int rl = lane & 15;
  const int c4 = (lane >> 4) << 2;
  const int swz = lane & 7;
  const int NT = K >> 6;

  auto stage = [&](int t, int buf) {
    const int k0 = t << 6;
#pragma unroll
    for (int i = 0; i < 2; ++i) {
      int c = tid + (i << 8);
      int r = c >> 3;
      int sch = (c & 7) ^ (r & 7);
      gl_lds16(Ag + (long)r * K + k0 + (sch << 3), &As[buf][c << 3]);
    }
#pragma unroll
    for (int i = 0; i < 8; ++i) {
      int c = tid + (i << 8);
      int r = c >> 3;
      int sch = (c & 7) ^ (r & 7);
      gl_lds16(Bt + (long)r * K + k0 + (sch << 3), &Bs[buf][c << 3]);
    }
  };

  stage(0, 0);
  __syncthreads();

  f32x4 acc[4][4] = {};
  int cur = 0;
  for (int t = 0; t < NT; ++t) {
    if (t + 1 < NT) stage(t + 1, cur ^ 1);
#pragma unroll
    for (int kt = 0; kt < 2; ++kt) {
      const int ko = ((kt * 4 + (lane >> 4)) ^ swz) << 3;
      bf16x8 av[4], bv[4];
#pragma unroll
      for (int mt = 0; mt < 4; ++mt)
        av[mt] = ldb8(&As[cur][(mt * 16 + rl) * 64 + ko]);
#pragma unroll
      for (int nt = 0; nt < 4; ++nt)
        bv[nt] = ldb8(&Bs[cur][(wc + nt * 16 + rl) * 64 + ko]);
#pragma unroll
      for (int mt = 0; mt < 4; ++mt)
#pragma unroll
        for (int nt = 0; nt < 4; ++nt)
          acc[mt][nt] = __builtin_amdgcn_mfma_f32_16x16x32_bf16(bv[nt], av[mt], acc[mt][nt], 0, 0, 0);
    }
    __syncthreads();
    cur ^= 1;
  }

  const long b = blockIdx.x;
  float s1[4] = {}, s2[4] = {};
#pragma unroll
  for (int nt = 0; nt < 4; ++nt) {
    const int col = wc + nt * 16 + c4;
    const f32x4 b4 = *(const f32x4*)(bias + col);
    const f32x4 g4 = ld_bf4(gptr + b * gstride + col);
#pragma unroll
    for (int mt = 0; mt < 4; ++mt) {
      const long row = tm + mt * 16 + rl;
      f32x4 x;
      if constexpr (XF32) x = *(const f32x4*)((const float*)xin + row * 256 + col);
      else x = ld_bf4((const u16*)xin + row * 256 + col);
      f32x4 xn = x + g4 * (acc[mt][nt] + b4);
      acc[mt][nt] = xn;
      s1[mt] += xn[0] + xn[1] + xn[2] + xn[3];
      s2[mt] += xn[0] * xn[0] + xn[1] * xn[1] + xn[2] * xn[2] + xn[3] * xn[3];
    }
  }
#pragma unroll
  for (int mt = 0; mt < 4; ++mt) {
    s1[mt] += __shfl_xor(s1[mt], 16); s1[mt] += __shfl_xor(s1[mt], 32);
    s2[mt] += __shfl_xor(s2[mt], 16); s2[mt] += __shfl_xor(s2[mt], 32);
  }
  float* st = (float*)&As[0][0];
  if (lane < 16) {
#pragma unroll
    for (int mt = 0; mt < 4; ++mt) {
      st[wave * 128 + mt * 16 + lane] = s1[mt];
      st[wave * 128 + 64 + mt * 16 + lane] = s2[mt];
    }
  }
  __syncthreads();
  float mean[4], rstd[4];
#pragma unroll
  for (int mt = 0; mt < 4; ++mt) {
    float a = 0.f, q = 0.f;
#pragma unroll
    for (int w2 = 0; w2 < 4; ++w2) {
      a += st[w2 * 128 + mt * 16 + rl];
      q += st[w2 * 128 + 64 + mt * 16 + rl];
    }
    mean[mt] = a * (1.f / 256.f);
    float var = q * (1.f / 256.f) - mean[mt] * mean[mt];
    rstd[mt] = rsqrtf(fmaxf(var, 0.f) + 1e-5f);
  }
#pragma unroll
  for (int nt = 0; nt < 4; ++nt) {
    const int col = wc + nt * 16 + c4;
    const f32x4 sc4 = ld_bf4(lnsc + b * lnstride + col);
    const f32x4 sh4 = ld_bf4(lnsh + b * lnstride + col);
#pragma unroll
    for (int mt = 0; mt < 4; ++mt) {
      const long row = tm + mt * 16 + rl;
      ushort4 xo;
      xo.x = f2b(acc[mt][nt][0]); xo.y = f2b(acc[mt][nt][1]);
      xo.z = f2b(acc[mt][nt][2]); xo.w = f2b(acc[mt][nt][3]);
      *(ushort4*)(xout + row * 256 + col) = xo;
      f32x4 h = (acc[mt][nt] - mean[mt]) * rstd[mt] * (1.f + sc4) + sh4;
      ushort4 o;
      o.x = f2b(h[0]); o.y = f2b(h[1]); o.z = f2b(h[2]); o.w = f2b(h[3]);
      *(ushort4*)(hout + row * 256 + col) = o;
    }
  }
}

// ---------------- fused FFN: x=x+g2*(mish(xln@W1^T+b1)@W2^T+b2); h=LN(x)*(1+sc)+sh ----------------
// Block processes TWO batch elems, software-pipelined (R15-proven). LDS 160KB (1 block/CU).
// T5: s_setprio(1) around MFMA clusters (wave role diversity between barriers).
__global__ __launch_bounds__(512)
void ffn_fused(const u16* __restrict__ xln, const u16* __restrict__ W1t,
               const float* __restrict__ b1, const u16* __restrict__ W2t,
               const float* __restrict__ b2, const u16* __restrict__ xres,
               const u16* __restrict__ gptr, int gstride,
               const u16* __restrict__ lnsh, const u16* __restrict__ lnsc, int lnstride,
               u16* __restrict__ xout, u16* __restrict__ hout) {
  __shared__ __align__(16) u16 Ax[64 * 256];
  __shared__ __align__(16) u16 Ws[2][256 * 64];
  __shared__ __align__(16) u16 H1[64 * 512];
  const int tid = threadIdx.x, lane = tid & 63, wave = tid >> 6;
  const long b0 = (long)blockIdx.x * 2;
  const int rl = lane & 15;
  const int c4 = (lane >> 4) << 2;
  const int kq = lane >> 4;

  auto stageAx = [&](long b) {
    const u16* src = xln + b * (64 * 256);
#pragma unroll
    for (int i = 0; i < 4; ++i) {
      int c = tid + (i << 9);
      int r = c >> 5, cc = c & 31;
      int sch = (cc & ~7) | ((cc & 7) ^ (r & 7));
      gl_lds16(src + r * 256 + (sch << 3), &Ax[c << 3]);
    }
  };
  auto stageW = [&](const u16* Wsrc, int Kw, int R0, int k0, int buf) {
#pragma unroll
    for (int i = 0; i < 4; ++i) {
      int c = tid + (i << 9);
      int r = c >> 3;
      int sch = (c & 7) ^ (r & 7);
      gl_lds16(Wsrc + (long)(R0 + r) * Kw + k0 + (sch << 3), &Ws[buf][c << 3]);
    }
  };

  stageAx(b0);
  stageW(W1t, 256, 0, 0, 0);
  __syncthreads();
  int cur = 0;

  for (int e = 0; e < 2; ++e) {
    const long b = b0 + e;
    // ---- phase A: h1 = mish(xln @ W1t^T + b1), two 256-col halves ----
    for (int nh = 0; nh < 2; ++nh) {
      f32x4 acc[4][2] = {};
      for (int t = 0; t < 4; ++t) {
        int s = nh * 4 + t;
        if (s < 7) stageW(W1t, 256, ((s + 1) >> 2) * 256, ((s + 1) & 3) * 64, cur ^ 1);
        else stageW(W2t, 512, 0, 0, cur ^ 1);  // prefetch phase-B tile 0
#pragma unroll
        for (int kt = 0; kt < 2; ++kt) {
          bf16x8 av[4], bv[2];
#pragma unroll
          for (int mt = 0; mt < 4; ++mt) {
            int r = mt * 16 + rl;
            int kc = t * 8 + kt * 4 + kq;
            int slot = (kc & ~7) | ((kc & 7) ^ (r & 7));
            av[mt] = ldb8(&Ax[r * 256 + (slot << 3)]);
          }
#pragma unroll
          for (int nf = 0; nf < 2; ++nf) {
            int wr_ = wave * 32 + nf * 16 + rl;
            int slot = (kt * 4 + kq) ^ (wr_ & 7);
            bv[nf] = ldb8(&Ws[cur][wr_ * 64 + (slot << 3)]);
          }
          __builtin_amdgcn_s_setprio(1);
#pragma unroll
          for (int mt = 0; mt < 4; ++mt)
#pragma unroll
            for (int nf = 0; nf < 2; ++nf)
              acc[mt][nf] = __builtin_amdgcn_mfma_f32_16x16x32_bf16(bv[nf], av[mt], acc[mt][nf], 0, 0, 0);
          __builtin_amdgcn_s_setprio(0);
        }
        __syncthreads();
        cur ^= 1;
      }
      // epilogue A: mish -> H1 (swizzled ds_write)
#pragma unroll
      for (int nf = 0; nf < 2; ++nf) {
        const int col = nh * 256 + wave * 32 + nf * 16 + c4;
        const f32x4 bb = *(const f32x4*)(b1 + col);
        const int c8 = col >> 3;
        const int sub = (col & 7) << 1;
#pragma unroll
        for (int mt = 0; mt < 4; ++mt) {
          const int r = mt * 16 + rl;
          f32x4 v = acc[mt][nf] + bb;
          ushort4 o;
          o.x = f2b(mishf(v[0])); o.y = f2b(mishf(v[1]));
          o.z = f2b(mishf(v[2])); o.w = f2b(mishf(v[3]));
          int slot = (c8 & ~7) | ((c8 & 7) ^ (r & 7));
          *(ushort4*)((char*)H1 + r * 1024 + (slot << 4) + sub) = o;
        }
      }
    }
    __syncthreads();  // H1 visible; W2 tile 0 staged; all Ax reads complete

    // ---- phase B: out = h1 @ W2t^T + b2; residual + LN ----
    f32x4 acc[4][2] = {};
    for (int t = 0; t < 8; ++t) {
      if (t < 7) stageW(W2t, 512, 0, (t + 1) * 64, cur ^ 1);
      else if (e == 0) stageW(W1t, 256, 0, 0, cur ^ 1);  // next elem's W1 tile 0
      if (t == 0 && e == 0) stageAx(b0 + 1);             // next elem's x (Ax dead)
#pragma unroll
      for (int kt = 0; kt < 2; ++kt) {
        bf16x8 av[4], bv[2];
#pragma unroll
        for (int mt = 0; mt < 4; ++mt) {
          int r = mt * 16 + rl;
          int kc = t * 8 + kt * 4 + kq;
          int slot = (kc & ~7) | ((kc & 7) ^ (r & 7));
          av[mt] = ldb8((const u16*)((const char*)H1 + r * 1024 + (slot << 4)));
        }
#pragma unroll
        for (int nf = 0; nf < 2; ++nf) {
          int wr_ = wave * 32 + nf * 16 + rl;
          int slot = (kt * 4 + kq) ^ (wr_ & 7);
          bv[nf] = ldb8(&Ws[cur][wr_ * 64 + (slot << 3)]);
        }
        __builtin_amdgcn_s_setprio(1);
#pragma unroll
        for (int mt = 0; mt < 4; ++mt)
#pragma unroll
          for (int nf = 0; nf < 2; ++nf)
            acc[mt][nf] = __builtin_amdgcn_mfma_f32_16x16x32_bf16(bv[nf], av[mt], acc[mt][nf], 0, 0, 0);
        __builtin_amdgcn_s_setprio(0);
      }
      __syncthreads();
      cur ^= 1;
    }
    // residual + row stats (wave's 32-col strip); stats scratch in H1 (dead after phase B)
    float s1[4] = {}, s2[4] = {};
#pragma unroll
    for (int nf = 0; nf < 2; ++nf) {
      const int col = wave * 32 + nf * 16 + c4;
      const f32x4 bb = *(const f32x4*)(b2 + col);
      const f32x4 g4 = ld_bf4(gptr + b * gstride + col);
#pragma unroll
      for (int mt = 0; mt < 4; ++mt) {
        const long row = b * 64 + mt * 16 + rl;
        f32x4 x = ld_bf4(xres + row * 256 + col);
        f32x4 xn = x + g4 * (acc[mt][nf] + bb);
        acc[mt][nf] = xn;
        s1[mt] += xn[0] + xn[1] + xn[2] + xn[3];
        s2[mt] += xn[0] * xn[0] + xn[1] * xn[1] + xn[2] * xn[2] + xn[3] * xn[3];
      }
    }
#pragma unroll
    for (int mt = 0; mt < 4; ++mt) {
      s1[mt] += __shfl_xor(s1[mt], 16); s1[mt] += __shfl_xor(s1[mt], 32);
      s2[mt] += __shfl_xor(s2[mt], 16); s2[mt] += __shfl_xor(s2[mt], 32);
    }
    float* st = (float*)&H1[0];
    if (lane < 16) {
#pragma unroll
      for (int mt = 0; mt < 4; ++mt) {
        st[wave * 128 + mt * 16 + lane] = s1[mt];
        st[wave * 128 + 64 + mt * 16 + lane] = s2[mt];
      }
    }
    __syncthreads();
    float mean[4], rstd[4];
#pragma unroll
    for (int mt = 0; mt < 4; ++mt) {
      float a = 0.f, q = 0.f;
#pragma unroll
      for (int w2 = 0; w2 < 8; ++w2) {
        a += st[w2 * 128 + mt * 16 + rl];
        q += st[w2 * 128 + 64 + mt * 16 + rl];
      }
      mean[mt] = a * (1.f / 256.f);
      float var = q * (1.f / 256.f) - mean[mt] * mean[mt];
      rstd[mt] = rsqrtf(fmaxf(var, 0.f) + 1e-5f);
    }
#pragma unroll
    for (int nf = 0; nf < 2; ++nf) {
      const int col = wave * 32 + nf * 16 + c4;
      const f32x4 sc4 = ld_bf4(lnsc + b * lnstride + col);
      const f32x4 sh4 = ld_bf4(lnsh + b * lnstride + col);
#pragma unroll
      for (int mt = 0; mt < 4; ++mt) {
        const long row = b * 64 + mt * 16 + rl;
        ushort4 xo;
        xo.x = f2b(acc[mt][nf][0]); xo.y = f2b(acc[mt][nf][1]);
        xo.z = f2b(acc[mt][nf][2]); xo.w = f2b(acc[mt][nf][3]);
        *(ushort4*)(xout + row * 256 + col) = xo;
        f32x4 h = (acc[mt][nf] - mean[mt]) * rstd[mt] * (1.f + sc4) + sh4;
        ushort4 o;
        o.x = f2b(h[0]); o.y = f2b(h[1]); o.z = f2b(h[2]); o.w = f2b(h[3]);
        *(ushort4*)(hout + row * 256 + col) = o;
      }
    }
    __syncthreads();  // stats reads done before next elem's epilogue-A overwrites H1
  }
}

// ---------------- fused attention: per (b, head-pair) block, wave=head ----------------
__global__ __launch_bounds__(128)
void attn_kernel(const u16* __restrict__ qkv, u16* __restrict__ out) {
  __shared__ __align__(16) u16 vt_s[2][64 * 72];
  __shared__ __align__(16) u16 p_s[2][64 * 72];
  const int lane = threadIdx.x & 63;
  const int wave = threadIdx.x >> 6;
  const long b = blockIdx.x >> 1;
  const int h = ((blockIdx.x & 1) << 1) | wave;
  u16* vt = vt_s[wave];
  u16* pl = p_s[wave];
  const u16* base = qkv + b * (64 * 768);
#pragma unroll
  for (int it = 0; it < 8; ++it) {
    int chunk = it * 64 + lane;
    int t = chunk >> 3, dhb = (chunk & 7) << 3;
    union { uint4 u; u16 s[8]; } uv;
    uv.u = *(const uint4*)(base + t * 768 + 512 + h * 64 + dhb);
#pragma unroll
    for (int j = 0; j < 8; ++j) vt[(dhb + j) * 72 + t] = uv.s[j];
  }
  const u16* qb = base + h * 64;
  const u16* kb = base + 256 + h * 64;
  f32x4 sacc[4][4] = {};
#pragma unroll
  for (int kt = 0; kt < 2; ++kt) {
    bf16x8 qa[4], kv[4];
#pragma unroll
    for (int mt = 0; mt < 4; ++mt)
      qa[mt] = ldb8(qb + ((lane & 15) + mt * 16) * 768 + kt * 32 + ((lane >> 4) << 3));
#pragma unroll
    for (int nt = 0; nt < 4; ++nt)
      kv[nt] = ldb8(kb + ((lane & 15) + nt * 16) * 768 + kt * 32 + ((lane >> 4) << 3));
#pragma unroll
    for (int mt = 0; mt < 4; ++mt)
#pragma unroll
      for (int nt = 0; nt < 4; ++nt)
        sacc[mt][nt] = __builtin_amdgcn_mfma_f32_16x16x32_bf16(qa[mt], kv[nt], sacc[mt][nt], 0, 0, 0);
  }
  const float scale = 0.125f;
#pragma unroll
  for (int mt = 0; mt < 4; ++mt) {
#pragma unroll
    for (int r = 0; r < 4; ++r) {
      float mx = fmaxf(fmaxf(sacc[mt][0][r], sacc[mt][1][r]), fmaxf(sacc[mt][2][r], sacc[mt][3][r]));
#pragma unroll
      for (int m = 1; m <= 8; m <<= 1) mx = fmaxf(mx, __shfl_xor(mx, m));
      float p[4];
      float sum = 0.f;
#pragma unroll
      for (int nt = 0; nt < 4; ++nt) { p[nt] = __expf((sacc[mt][nt][r] - mx) * scale); sum += p[nt]; }
#pragma unroll
      for (int m = 1; m <= 8; m <<= 1) sum += __shfl_xor(sum, m);
      const float rinv = 1.f / sum;
      const int s = mt * 16 + ((lane >> 4) << 2) + r;
#pragma unroll
      for (int nt = 0; nt < 4; ++nt) pl[s * 72 + nt * 16 + (lane & 15)] = f2b(p[nt] * rinv);
    }
  }
  __syncthreads();
  f32x4 oacc[4][4] = {};
#pragma unroll
  for (int kt = 0; kt < 2; ++kt) {
    bf16x8 pa[4], vv[4];
#pragma unroll
    for (int mt = 0; mt < 4; ++mt)
      pa[mt] = ldb8(pl + ((lane & 15) + mt * 16) * 72 + kt * 32 + ((lane >> 4) << 3));
#pragma unroll
    for (int nt = 0; nt < 4; ++nt)
      vv[nt] = ldb8(vt + ((lane & 15) + nt * 16) * 72 + kt * 32 + ((lane >> 4) << 3));
#pragma unroll
    for (int mt = 0; mt < 4; ++mt)
#pragma unroll
      for (int nt = 0; nt < 4; ++nt)
        oacc[mt][nt] = __builtin_amdgcn_mfma_f32_16x16x32_bf16(vv[nt], pa[mt], oacc[mt][nt], 0, 0, 0);
  }
  u16* ob = out + b * (64 * 256) + h * 64;
#pragma unroll
  for (int mt = 0; mt < 4; ++mt)
#pragma unroll
    for (int nt = 0; nt < 4; ++nt) {
      const int s = mt * 16 + (lane & 15);
      const int d4 = nt * 16 + ((lane >> 4) << 2);
      ushort4 o;
      o.x = f2b(oacc[mt][nt][0]); o.y = f2b(oacc[mt][nt][1]);
      o.z = f2b(oacc[mt][nt][2]); o.w = f2b(oacc[mt][nt][3]);
      *(ushort4*)(ob + s * 256 + d4) = o;
    }
}

extern "C" void kernel_launch(void* const* d_in, const int* in_sizes, int n_in,
                              void* d_out, int out_size, void* d_ws, size_t ws_size,
                              hipStream_t stream) {
  (void)in_sizes; (void)n_in; (void)out_size; (void)ws_size;
  const int B = 4096, L = 6;
  const long BSr = (long)B * 64;

  const float* x_t = (const float*)d_in[0];
  const int* tvec = (const int*)d_in[1];
  const float* backbone = (const float*)d_in[2];
  const float* emb = (const float*)d_in[3];
  const float* te_w1 = (const float*)d_in[4];
  const float* te_b1 = (const float*)d_in[5];
  const float* te_w2 = (const float*)d_in[6];
  const float* te_b2 = (const float*)d_in[7];
  const float* cp_w1 = (const float*)d_in[8];
  const float* cp_b1 = (const float*)d_in[9];
  const float* cp_w2 = (const float*)d_in[10];
  const float* cp_b2 = (const float*)d_in[11];
  const float* adaln_w = (const float*)d_in[12];
  const float* adaln_b = (const float*)d_in[13];
  const float* qkv_w = (const float*)d_in[14];
  const float* qkv_b = (const float*)d_in[15];
  const float* op_w = (const float*)d_in[16];
  const float* op_b = (const float*)d_in[17];
  const float* ffn_w1 = (const float*)d_in[18];
  const float* ffn_b1 = (const float*)d_in[19];
  const float* ffn_w2 = (const float*)d_in[20];
  const float* ffn_b2 = (const float*)d_in[21];
  const float* fa_w = (const float*)d_in[22];
  const float* fa_b = (const float*)d_in[23];
  const float* fp_w = (const float*)d_in[24];
  const float* fp_b = (const float*)d_in[25];

  char* w = (char*)d_ws;
  auto alloc = [&](size_t bytes) { char* p = w; w += (bytes + 255) & ~(size_t)255; return p; };
  u16* WT_cp1 = (u16*)alloc(256L * 512 * 2);
  u16* WT_cp2 = (u16*)alloc(256L * 256 * 2);
  u16* WT_adaln = (u16*)alloc(6L * 1536 * 256 * 2);  // = [9216][256] B^T
  u16* WT_qkv = (u16*)alloc(6L * 768 * 256 * 2);
  u16* WT_op = (u16*)alloc(6L * 256 * 256 * 2);
  u16* WT_f1 = (u16*)alloc(6L * 512 * 256 * 2);
  u16* WT_f2 = (u16*)alloc(6L * 256 * 512 * 2);
  u16* WT_fa = (u16*)alloc(512L * 256 * 2);
  u16* WT_fp = (u16*)alloc(256L * 256 * 2);
  float* te_tab = (float*)alloc(21L * 256 * 4);
  u16* cond = (u16*)alloc(4096L * 512 * 2);
  u16* c1 = (u16*)alloc(4096L * 256 * 2);
  u16* mc = (u16*)alloc(4096L * 256 * 2);
  u16* modb6 = (u16*)alloc(4096L * 9216 * 2);  // batch-major [4096][6*1536]
  u16* famod = (u16*)alloc(4096L * 512 * 2);
  u16* hbuf = (u16*)alloc(BSr * 256 * 2);
  u16* qkvbuf = (u16*)alloc(BSr * 768 * 2);
  u16* xbuf = (u16*)d_out;  // bf16 residual stream in d_out storage

  transpose_w<<<dim3(4, 8, 1), 256, 0, stream>>>(cp_w1, WT_cp1, 512, 256);
  transpose_w<<<dim3(4, 4, 1), 256, 0, stream>>>(cp_w2, WT_cp2, 256, 256);
  transpose_w<<<dim3(24, 4, 6), 256, 0, stream>>>(adaln_w, WT_adaln, 256, 1536);
  transpose_w<<<dim3(12, 4, 6), 256, 0, stream>>>(qkv_w, WT_qkv, 256, 768);
  transpose_w<<<dim3(4, 4, 6), 256, 0, stream>>>(op_w, WT_op, 256, 256);
  transpose_w<<<dim3(8, 4, 6), 256, 0, stream>>>(ffn_w1, WT_f1, 256, 512);
  transpose_w<<<dim3(4, 8, 6), 256, 0, stream>>>(ffn_w2, WT_f2, 512, 256);
  transpose_w<<<dim3(8, 4, 1), 256, 0, stream>>>(fa_w, WT_fa, 256, 512);
  transpose_w<<<dim3(4, 4, 1), 256, 0, stream>>>(fp_w, WT_fp, 256, 256);

  te_table_kernel<<<21, 1024, 0, stream>>>(emb, te_w1, te_b1, te_w2, te_b2, te_tab);
  cond_mean_kernel<<<4096, 256, 0, stream>>>(backbone, cond);

  gemm_bt<1><<<dim3(2, 32), 256, 0, stream>>>(cond, WT_cp1, cp_b1, c1, nullptr, nullptr, 4096, 256, 512);
  gemm_bt<4><<<dim3(2, 32), 256, 0, stream>>>(c1, WT_cp2, cp_b2, mc, tvec, te_tab, 4096, 256, 256);
  gemm_bt<0><<<dim3(4, 32), 256, 0, stream>>>(mc, WT_fa, fa_b, famod, nullptr, nullptr, 4096, 512, 256);
  // single adaLN GEMM over all 6 layers: N = 6*1536 = 9216 (2304 blocks)
  gemm_bt<0><<<dim3(72, 32), 256, 0, stream>>>(mc, WT_adaln, adaln_b, modb6, nullptr, nullptr, 4096, 9216, 256);

  // layer-0 input LN (sh1/sc1)
  ln_mod<<<BSr / 4, 256, 0, stream>>>(x_t, modb6, 9216, 0, 256, hbuf);

  for (int l = 0; l < L; ++l) {
    const u16* mb = modb6 + (long)l * 1536;  // batch-major: row stride 9216
    gemm_bt<0><<<dim3(6, BSr / 128), 256, 0, stream>>>(hbuf, WT_qkv + (long)l * 768 * 256, qkv_b + l * 768,
                                                       qkvbuf, nullptr, nullptr, (int)BSr, 768, 256);
    attn_kernel<<<B * 2, 128, 0, stream>>>(qkvbuf, hbuf);
    // x = xin + g1*(attn_out @ Wop + b); h = LN(x)*(1+sc2)+sh2
    if (l == 0)
      gemm_ln<256, true><<<BSr / 64, 256, 0, stream>>>(hbuf, WT_op, op_b, x_t, mb + 512, 9216,
                                                       mb + 768, mb + 1024, 9216, xbuf, hbuf);
    else
      gemm_ln<256, false><<<BSr / 64, 256, 0, stream>>>(hbuf, WT_op + (long)l * 256 * 256, op_b + l * 256,
                                                        xbuf, mb + 512, 9216, mb + 768, mb + 1024, 9216, xbuf, hbuf);
    // fused FFN1+FFN2 + residual + next-layer LN (2 elems per block, pipelined)
    const u16* nsh = (l < 5) ? (mb + 1536) : famod;
    const u16* nsc = (l < 5) ? (mb + 1536 + 256) : (famod + 256);
    const int nstride = (l < 5) ? 9216 : 512;
    ffn_fused<<<BSr / 128, 512, 0, stream>>>(hbuf, WT_f1 + (long)l * 512 * 256, ffn_b1 + l * 512,
                                             WT_f2 + (long)l * 256 * 512, ffn_b2 + l * 256,
                                             xbuf, mb + 1280, 9216, nsh, nsc, nstride, xbuf, hbuf);
  }
  gemm_bt<3><<<dim3(2, BSr / 128), 256, 0, stream>>>(hbuf, WT_fp, fp_b, d_out, nullptr, nullptr, (int)BSr, 256, 256);
}

// Round 21
// 6225.043 us; speedup vs baseline: 1.0483x; 1.0024x over previous
//
#include <hip/hip_runtime.h>

typedef unsigned short u16;
typedef float f32x4 __attribute__((ext_vector_type(4)));
typedef __bf16 bf16x8 __attribute__((ext_vector_type(8)));

__device__ __forceinline__ u16 f2b(float f) {
  unsigned u = __builtin_bit_cast(unsigned, f);
  u += 0x7FFF + ((u >> 16) & 1);
  return (u16)(u >> 16);
}

__device__ __forceinline__ float b2f(u16 v) {
  unsigned u = (unsigned)v << 16;
  return __builtin_bit_cast(float, u);
}

__device__ __forceinline__ f32x4 ld_bf4(const u16* p) {
  ushort4 v = *(const ushort4*)p;
  f32x4 r;
  r[0] = b2f(v.x); r[1] = b2f(v.y); r[2] = b2f(v.z); r[3] = b2f(v.w);
  return r;
}

// mish(x) = x * tanh(softplus(x)) = x * (e^2+2e)/(e^2+2e+2), e = exp(x)
__device__ __forceinline__ float mishf(float x) {
  float e = __expf(fminf(x, 20.f));
  float n = e * (e + 2.f);
  return x * __fdividef(n, n + 2.f);
}

__device__ __forceinline__ void gl_lds16(const void* g, void* l) {
  __builtin_amdgcn_global_load_lds((__attribute__((address_space(1))) void*)g,
                                   (__attribute__((address_space(3))) void*)l, 16, 0, 0);
}

__device__ __forceinline__ bf16x8 ldb8(const u16* p) {
  return __builtin_bit_cast(bf16x8, *(const uint4*)p);
}

// ---------------- weight transpose f32[K,N] -> bf16[N,K] ----------------
__global__ __launch_bounds__(256)
void transpose_w(const float* __restrict__ in, u16* __restrict__ out, int K, int N) {
  __shared__ float tl[64][65];
  const long zoff = (long)blockIdx.z * K * N;
  in += zoff; out += zoff;
  const int n0 = blockIdx.x * 64, k0 = blockIdx.y * 64;
  const int c = threadIdx.x & 63, r0 = threadIdx.x >> 6;
#pragma unroll
  for (int i = 0; i < 16; ++i) {
    int r = i * 4 + r0;
    tl[r][c] = in[(long)(k0 + r) * N + n0 + c];
  }
  __syncthreads();
#pragma unroll
  for (int i = 0; i < 16; ++i) {
    int r = i * 4 + r0;
    out[(long)(n0 + r) * K + k0 + c] = f2b(tl[c][r]);
  }
}

// ---------------- timestep-embedding MLP table (21 rows) ----------------
__global__ __launch_bounds__(1024)
void te_table_kernel(const float* __restrict__ emb, const float* __restrict__ w1,
                     const float* __restrict__ b1, const float* __restrict__ w2,
                     const float* __restrict__ b2, float* __restrict__ table) {
  __shared__ float te[256];
  __shared__ float h1[1024];
  __shared__ float red[1024];
  const int tt = blockIdx.x, tid = threadIdx.x;
  if (tid < 256) te[tid] = emb[tt * 256 + tid];
  __syncthreads();
  float a = b1[tid];
#pragma unroll 8
  for (int k = 0; k < 256; ++k) a += te[k] * w1[k * 1024 + tid];
  h1[tid] = mishf(a);
  __syncthreads();
  const int j = tid & 255, kq = tid >> 8;
  float a2 = 0.f;
#pragma unroll 8
  for (int k = kq * 256; k < kq * 256 + 256; ++k) a2 += h1[k] * w2[k * 256 + j];
  red[tid] = a2;
  __syncthreads();
  if (tid < 256)
    table[tt * 256 + tid] = b2[tid] + red[tid] + red[tid + 256] + red[tid + 512] + red[tid + 768];
}

// ---------------- cond = mean over S, written bf16 ----------------
__global__ __launch_bounds__(256)
void cond_mean_kernel(const float* __restrict__ bb, u16* __restrict__ cond) {
  const int b = blockIdx.x, tid = threadIdx.x;
  const float* p = bb + (long)b * 64 * 512;
  for (int d = tid; d < 512; d += 256) {
    float s = 0.f;
#pragma unroll
    for (int t = 0; t < 64; ++t) s += p[t * 512 + d];
    cond[b * 512 + d] = f2b(s * (1.f / 64.f));
  }
}

// ---------------- LayerNorm + adaLN modulate -> bf16 (layer-0 input; mod is bf16) ----------------
__global__ __launch_bounds__(256)
void ln_mod(const float* __restrict__ x, const u16* __restrict__ modb,
            int mstride, int shoff, int scoff, u16* __restrict__ out) {
  const int lane = threadIdx.x & 63;
  const long row = (long)blockIdx.x * 4 + (threadIdx.x >> 6);
  const float4 xv = *(const float4*)(x + row * 256 + lane * 4);
  float s1 = xv.x + xv.y + xv.z + xv.w;
  float s2 = xv.x * xv.x + xv.y * xv.y + xv.z * xv.z + xv.w * xv.w;
#pragma unroll
  for (int m = 1; m < 64; m <<= 1) { s1 += __shfl_xor(s1, m); s2 += __shfl_xor(s2, m); }
  const float mean = s1 * (1.f / 256.f);
  float var = s2 * (1.f / 256.f) - mean * mean;
  const float rstd = rsqrtf(fmaxf(var, 0.f) + 1e-5f);
  const long b = row >> 6;
  const f32x4 sc = ld_bf4(modb + b * mstride + scoff + lane * 4);
  const f32x4 sh = ld_bf4(modb + b * mstride + shoff + lane * 4);
  ushort4 o;
  o.x = f2b((xv.x - mean) * rstd * (1.f + sc[0]) + sh[0]);
  o.y = f2b((xv.y - mean) * rstd * (1.f + sc[1]) + sh[1]);
  o.z = f2b((xv.z - mean) * rstd * (1.f + sc[2]) + sh[2]);
  o.w = f2b((xv.w - mean) * rstd * (1.f + sc[3]) + sh[3]);
  *(ushort4*)(out + row * 256 + lane * 4) = o;
}

// ---------------- GEMM: C[M,N] = A[M,K](bf16) @ Bt[N,K]^T(bf16) + epilogue ----------------
// EPI 0: +bias -> bf16 | 1: mish(+bias) -> bf16 | 3: +bias -> f32
// EPI 4: mish(+bias + te_table[t[row]]) -> bf16
// XSWZ: XCD-aware remap so the gridDim.x blocks sharing one A-tile land on one XCD
// (bijective for gridDim.y % 8 == 0; affects locality only, not correctness).
template <int EPI, bool XSWZ = false>
__global__ __launch_bounds__(256)
void gemm_bt(const u16* __restrict__ A, const u16* __restrict__ Bt,
             const float* __restrict__ bias, void* __restrict__ outp,
             const int* __restrict__ tvec, const float* __restrict__ tetab,
             int M, int N, int K) {
  __shared__ __align__(16) u16 As[2][128 * 64];
  __shared__ __align__(16) u16 Bs[2][128 * 64];
  const int tid = threadIdx.x;
  const int lane = tid & 63;
  const int wave = tid >> 6;
  const int wr = (wave >> 1) << 6;
  const int wc = (wave & 1) << 6;
  long tm, tn;
  if constexpr (XSWZ) {
    const int NX = gridDim.x;
    const int d = blockIdx.y * NX + blockIdx.x;
    const int r = d & 7, q = d >> 3;
    const int gq = q / NX, i = q % NX;
    tm = (long)(gq * 8 + r) * 128;
    tn = (long)i * 128;
  } else {
    tm = (long)blockIdx.y * 128;
    tn = (long)blockIdx.x * 128;
  }
  const u16* Ag = A + tm * K;
  const u16* Bg = Bt + tn * K;
  f32x4 acc[4][4] = {};
  const int kcb = lane >> 4;
  const int swz = lane & 7;
  const int NT = K >> 6;

  auto stage = [&](int t, int buf) {
    const int k0 = t << 6;
#pragma unroll
    for (int i = 0; i < 4; ++i) {
      int c = tid + (i << 8);
      int r = c >> 3;
      int sch = (c & 7) ^ (r & 7);
      gl_lds16(Ag + (long)r * K + k0 + (sch << 3), &As[buf][c << 3]);
    }
#pragma unroll
    for (int i = 0; i < 4; ++i) {
      int c = tid + (i << 8);
      int r = c >> 3;
      int sch = (c & 7) ^ (r & 7);
      gl_lds16(Bg + (long)r * K + k0 + (sch << 3), &Bs[buf][c << 3]);
    }
  };

  stage(0, 0);
  __syncthreads();
  int cur = 0;
  for (int t = 0; t < NT; ++t) {
    if (t + 1 < NT) stage(t + 1, cur ^ 1);
#pragma unroll
    for (int kt = 0; kt < 2; ++kt) {
      const int ko = ((kt * 4 + kcb) ^ swz) << 3;
      bf16x8 av[4], bv[4];
#pragma unroll
      for (int mt = 0; mt < 4; ++mt)
        av[mt] = ldb8(&As[cur][(wr + mt * 16 + (lane & 15)) * 64 + ko]);
#pragma unroll
      for (int nt = 0; nt < 4; ++nt)
        bv[nt] = ldb8(&Bs[cur][(wc + nt * 16 + (lane & 15)) * 64 + ko]);
#pragma unroll
      for (int mt = 0; mt < 4; ++mt)
#pragma unroll
        for (int nt = 0; nt < 4; ++nt)
          acc[mt][nt] = __builtin_amdgcn_mfma_f32_16x16x32_bf16(bv[nt], av[mt], acc[mt][nt], 0, 0, 0);
    }
    __syncthreads();
    cur ^= 1;
  }
  const int rl = lane & 15;
  const int c4 = (lane >> 4) << 2;
  f32x4 b4[4];
#pragma unroll
  for (int nt = 0; nt < 4; ++nt)
    b4[nt] = *(const f32x4*)(bias + (int)tn + wc + nt * 16 + c4);
#pragma unroll
  for (int mt = 0; mt < 4; ++mt) {
    const unsigned row = (unsigned)(tm + wr + mt * 16 + rl);
    const unsigned rb = row * (unsigned)N;
#pragma unroll
    for (int nt = 0; nt < 4; ++nt) {
      const unsigned col = (unsigned)tn + wc + nt * 16 + c4;
      f32x4 v = acc[mt][nt] + b4[nt];
      if constexpr (EPI == 0) {
        ushort4 o;
        o.x = f2b(v[0]); o.y = f2b(v[1]); o.z = f2b(v[2]); o.w = f2b(v[3]);
        *(ushort4*)((u16*)outp + rb + col) = o;
      } else if constexpr (EPI == 1) {
        ushort4 o;
        o.x = f2b(mishf(v[0])); o.y = f2b(mishf(v[1]));
        o.z = f2b(mishf(v[2])); o.w = f2b(mishf(v[3]));
        *(ushort4*)((u16*)outp + rb + col) = o;
      } else if constexpr (EPI == 3) {
        *(f32x4*)((float*)outp + rb + col) = v;
      } else {
        const f32x4 te = *(const f32x4*)(tetab + tvec[row] * 256 + col);
        ushort4 o;
        o.x = f2b(mishf(v[0] + te[0])); o.y = f2b(mishf(v[1] + te[1]));
        o.z = f2b(mishf(v[2] + te[2])); o.w = f2b(mishf(v[3] + te[3]));
        *(ushort4*)((u16*)outp + rb + col) = o;
      }
    }
  }
}

// ---------------- GEMM (N=256 full rows) + residual + LayerNorm + modulate ----------------
// (op-projection stage) 256 thr / 4 waves; block = 64 rows. Residual bf16; mods bf16.
template <int K, bool XF32>
__global__ __launch_bounds__(256)
void gemm_ln(const u16* __restrict__ A, const u16* __restrict__ Bt,
             const float* __restrict__ bias, const void* __restrict__ xin,
             const u16* __restrict__ gptr, int gstride,
             const u16* __restrict__ lnsh, const u16* __restrict__ lnsc, int lnstride,
             u16* __restrict__ xout, u16* __restrict__ hout) {
  __shared__ __align__(16) u16 As[2][64 * 64];
  __shared__ __align__(16) u16 Bs[2][256 * 64];
  const int tid = threadIdx.x, lane = tid & 63, wave = tid >> 6;
  const int wc = wave << 6;
  const long tm = (long)blockIdx.x * 64;
  const u16* Ag = A + tm * K;
  const int rl = lane & 15;
  const int c4 = (lane >> 4) << 2;
  const int swz = lane & 7;
  const int NT = K >> 6;

  auto stage = [&](int t, int buf) {
    const int k0 = t << 6;
#pragma unroll
    for (int i = 0; i < 2; ++i) {
      int c = tid + (i << 8);
      int r = c >> 3;
      int sch = (c & 7) ^ (r & 7);
      gl_lds16(Ag + (long)r * K + k0 + (sch << 3), &As[buf][c << 3]);
    }
#pragma unroll
    for (int i = 0; i < 8; ++i) {
      int c = tid + (i << 8);
      int r = c >> 3;
      int sch = (c & 7) ^ (r & 7);
      gl_lds16(Bt + (long)r * K + k0 + (sch << 3), &Bs[buf][c << 3]);
    }
  };

  stage(0, 0);
  __syncthreads();

  f32x4 acc[4][4] = {};
  int cur = 0;
  for (int t = 0; t < NT; ++t) {
    if (t + 1 < NT) stage(t + 1, cur ^ 1);
#pragma unroll
    for (int kt = 0; kt < 2; ++kt) {
      const int ko = ((kt * 4 + (lane >> 4)) ^ swz) << 3;
      bf16x8 av[4], bv[4];
#pragma unroll
      for (int mt = 0; mt < 4; ++mt)
        av[mt] = ldb8(&As[cur][(mt * 16 + rl) * 64 + ko]);
#pragma unroll
      for (int nt = 0; nt < 4; ++nt)
        bv[nt] = ldb8(&Bs[cur][(wc + nt * 16 + rl) * 64 + ko]);
#pragma unroll
      for (int mt = 0; mt < 4; ++mt)
#pragma unroll
        for (int nt = 0; nt < 4; ++nt)
          acc[mt][nt] = __builtin_amdgcn_mfma_f32_16x16x32_bf16(bv[nt], av[mt], acc[mt][nt], 0, 0, 0);
    }
    __syncthreads();
    cur ^= 1;
  }

  const long b = blockIdx.x;
  float s1[4] = {}, s2[4] = {};
#pragma unroll
  for (int nt = 0; nt < 4; ++nt) {
    const int col = wc + nt * 16 + c4;
    const f32x4 b4 = *(const f32x4*)(bias + col);
    const f32x4 g4 = ld_bf4(gptr + b * gstride + col);
#pragma unroll
    for (int mt = 0; mt < 4; ++mt) {
      const long row = tm + mt * 16 + rl;
      f32x4 x;
      if constexpr (XF32) x = *(const f32x4*)((const float*)xin + row * 256 + col);
      else x = ld_bf4((const u16*)xin + row * 256 + col);
      f32x4 xn = x + g4 * (acc[mt][nt] + b4);
      acc[mt][nt] = xn;
      s1[mt] += xn[0] + xn[1] + xn[2] + xn[3];
      s2[mt] += xn[0] * xn[0] + xn[1] * xn[1] + xn[2] * xn[2] + xn[3] * xn[3];
    }
  }
#pragma unroll
  for (int mt = 0; mt < 4; ++mt) {
    s1[mt] += __shfl_xor(s1[mt], 16); s1[mt] += __shfl_xor(s1[mt], 32);
    s2[mt] += __shfl_xor(s2[mt], 16); s2[mt] += __shfl_xor(s2[mt], 32);
  }
  float* st = (float*)&As[0][0];
  if (lane < 16) {
#pragma unroll
    for (int mt = 0; mt < 4; ++mt) {
      st[wave * 128 + mt * 16 + lane] = s1[mt];
      st[wave * 128 + 64 + mt * 16 + lane] = s2[mt];
    }
  }
  __syncthreads();
  float mean[4], rstd[4];
#pragma unroll
  for (int mt = 0; mt < 4; ++mt) {
    float a = 0.f, q = 0.f;
#pragma unroll
    for (int w2 = 0; w2 < 4; ++w2) {
      a += st[w2 * 128 + mt * 16 + rl];
      q += st[w2 * 128 + 64 + mt * 16 + rl];
    }
    mean[mt] = a * (1.f / 256.f);
    float var = q * (1.f / 256.f) - mean[mt] * mean[mt];
    rstd[mt] = rsqrtf(fmaxf(var, 0.f) + 1e-5f);
  }
#pragma unroll
  for (int nt = 0; nt < 4; ++nt) {
    const int col = wc + nt * 16 + c4;
    const f32x4 sc4 = ld_bf4(lnsc + b * lnstride + col);
    const f32x4 sh4 = ld_bf4(lnsh + b * lnstride + col);
#pragma unroll
    for (int mt = 0; mt < 4; ++mt) {
      const long row = tm + mt * 16 + rl;
      ushort4 xo;
      xo.x = f2b(acc[mt][nt][0]); xo.y = f2b(acc[mt][nt][1]);
      xo.z = f2b(acc[mt][nt][2]); xo.w = f2b(acc[mt][nt][3]);
      *(ushort4*)(xout + row * 256 + col) = xo;
      f32x4 h = (acc[mt][nt] - mean[mt]) * rstd[mt] * (1.f + sc4) + sh4;
      ushort4 o;
      o.x = f2b(h[0]); o.y = f2b(h[1]); o.z = f2b(h[2]); o.w = f2b(h[3]);
      *(ushort4*)(hout + row * 256 + col) = o;
    }
  }
}

// ---------------- fused FFN: x=x+g2*(mish(xln@W1^T+b1)@W2^T+b2); h=LN(x)*(1+sc)+sh ----------------
// Block processes TWO batch elems, software-pipelined (R15-proven). LDS 160KB (1 block/CU).
__global__ __launch_bounds__(512)
void ffn_fused(const u16* __restrict__ xln, const u16* __restrict__ W1t,
               const float* __restrict__ b1, const u16* __restrict__ W2t,
               const float* __restrict__ b2, const u16* __restrict__ xres,
               const u16* __restrict__ gptr, int gstride,
               const u16* __restrict__ lnsh, const u16* __restrict__ lnsc, int lnstride,
               u16* __restrict__ xout, u16* __restrict__ hout) {
  __shared__ __align__(16) u16 Ax[64 * 256];
  __shared__ __align__(16) u16 Ws[2][256 * 64];
  __shared__ __align__(16) u16 H1[64 * 512];
  const int tid = threadIdx.x, lane = tid & 63, wave = tid >> 6;
  const long b0 = (long)blockIdx.x * 2;
  const int rl = lane & 15;
  const int c4 = (lane >> 4) << 2;
  const int kq = lane >> 4;

  auto stageAx = [&](long b) {
    const u16* src = xln + b * (64 * 256);
#pragma unroll
    for (int i = 0; i < 4; ++i) {
      int c = tid + (i << 9);
      int r = c >> 5, cc = c & 31;
      int sch = (cc & ~7) | ((cc & 7) ^ (r & 7));
      gl_lds16(src + r * 256 + (sch << 3), &Ax[c << 3]);
    }
  };
  auto stageW = [&](const u16* Wsrc, int Kw, int R0, int k0, int buf) {
#pragma unroll
    for (int i = 0; i < 4; ++i) {
      int c = tid + (i << 9);
      int r = c >> 3;
      int sch = (c & 7) ^ (r & 7);
      gl_lds16(Wsrc + (long)(R0 + r) * Kw + k0 + (sch << 3), &Ws[buf][c << 3]);
    }
  };

  stageAx(b0);
  stageW(W1t, 256, 0, 0, 0);
  __syncthreads();
  int cur = 0;

  for (int e = 0; e < 2; ++e) {
    const long b = b0 + e;
    // ---- phase A: h1 = mish(xln @ W1t^T + b1), two 256-col halves ----
    for (int nh = 0; nh < 2; ++nh) {
      f32x4 acc[4][2] = {};
      for (int t = 0; t < 4; ++t) {
        int s = nh * 4 + t;
        if (s < 7) stageW(W1t, 256, ((s + 1) >> 2) * 256, ((s + 1) & 3) * 64, cur ^ 1);
        else stageW(W2t, 512, 0, 0, cur ^ 1);  // prefetch phase-B tile 0
#pragma unroll
        for (int kt = 0; kt < 2; ++kt) {
          bf16x8 av[4], bv[2];
#pragma unroll
          for (int mt = 0; mt < 4; ++mt) {
            int r = mt * 16 + rl;
            int kc = t * 8 + kt * 4 + kq;
            int slot = (kc & ~7) | ((kc & 7) ^ (r & 7));
            av[mt] = ldb8(&Ax[r * 256 + (slot << 3)]);
          }
#pragma unroll
          for (int nf = 0; nf < 2; ++nf) {
            int wr_ = wave * 32 + nf * 16 + rl;
            int slot = (kt * 4 + kq) ^ (wr_ & 7);
            bv[nf] = ldb8(&Ws[cur][wr_ * 64 + (slot << 3)]);
          }
          __builtin_amdgcn_s_setprio(1);
#pragma unroll
          for (int mt = 0; mt < 4; ++mt)
#pragma unroll
            for (int nf = 0; nf < 2; ++nf)
              acc[mt][nf] = __builtin_amdgcn_mfma_f32_16x16x32_bf16(bv[nf], av[mt], acc[mt][nf], 0, 0, 0);
          __builtin_amdgcn_s_setprio(0);
        }
        __syncthreads();
        cur ^= 1;
      }
      // epilogue A: mish -> H1 (swizzled ds_write)
#pragma unroll
      for (int nf = 0; nf < 2; ++nf) {
        const int col = nh * 256 + wave * 32 + nf * 16 + c4;
        const f32x4 bb = *(const f32x4*)(b1 + col);
        const int c8 = col >> 3;
        const int sub = (col & 7) << 1;
#pragma unroll
        for (int mt = 0; mt < 4; ++mt) {
          const int r = mt * 16 + rl;
          f32x4 v = acc[mt][nf] + bb;
          ushort4 o;
          o.x = f2b(mishf(v[0])); o.y = f2b(mishf(v[1]));
          o.z = f2b(mishf(v[2])); o.w = f2b(mishf(v[3]));
          int slot = (c8 & ~7) | ((c8 & 7) ^ (r & 7));
          *(ushort4*)((char*)H1 + r * 1024 + (slot << 4) + sub) = o;
        }
      }
    }
    __syncthreads();  // H1 visible; W2 tile 0 staged; all Ax reads complete

    // ---- phase B: out = h1 @ W2t^T + b2; residual + LN ----
    f32x4 acc[4][2] = {};
    for (int t = 0; t < 8; ++t) {
      if (t < 7) stageW(W2t, 512, 0, (t + 1) * 64, cur ^ 1);
      else if (e == 0) stageW(W1t, 256, 0, 0, cur ^ 1);  // next elem's W1 tile 0
      if (t == 0 && e == 0) stageAx(b0 + 1);             // next elem's x (Ax dead)
#pragma unroll
      for (int kt = 0; kt < 2; ++kt) {
        bf16x8 av[4], bv[2];
#pragma unroll
        for (int mt = 0; mt < 4; ++mt) {
          int r = mt * 16 + rl;
          int kc = t * 8 + kt * 4 + kq;
          int slot = (kc & ~7) | ((kc & 7) ^ (r & 7));
          av[mt] = ldb8((const u16*)((const char*)H1 + r * 1024 + (slot << 4)));
        }
#pragma unroll
        for (int nf = 0; nf < 2; ++nf) {
          int wr_ = wave * 32 + nf * 16 + rl;
          int slot = (kt * 4 + kq) ^ (wr_ & 7);
          bv[nf] = ldb8(&Ws[cur][wr_ * 64 + (slot << 3)]);
        }
        __builtin_amdgcn_s_setprio(1);
#pragma unroll
        for (int mt = 0; mt < 4; ++mt)
#pragma unroll
          for (int nf = 0; nf < 2; ++nf)
            acc[mt][nf] = __builtin_amdgcn_mfma_f32_16x16x32_bf16(bv[nf], av[mt], acc[mt][nf], 0, 0, 0);
        __builtin_amdgcn_s_setprio(0);
      }
      __syncthreads();
      cur ^= 1;
    }
    // residual + row stats (wave's 32-col strip); stats scratch in H1 (dead after phase B)
    float s1[4] = {}, s2[4] = {};
#pragma unroll
    for (int nf = 0; nf < 2; ++nf) {
      const int col = wave * 32 + nf * 16 + c4;
      const f32x4 bb = *(const f32x4*)(b2 + col);
      const f32x4 g4 = ld_bf4(gptr + b * gstride + col);
#pragma unroll
      for (int mt = 0; mt < 4; ++mt) {
        const long row = b * 64 + mt * 16 + rl;
        f32x4 x = ld_bf4(xres + row * 256 + col);
        f32x4 xn = x + g4 * (acc[mt][nf] + bb);
        acc[mt][nf] = xn;
        s1[mt] += xn[0] + xn[1] + xn[2] + xn[3];
        s2[mt] += xn[0] * xn[0] + xn[1] * xn[1] + xn[2] * xn[2] + xn[3] * xn[3];
      }
    }
#pragma unroll
    for (int mt = 0; mt < 4; ++mt) {
      s1[mt] += __shfl_xor(s1[mt], 16); s1[mt] += __shfl_xor(s1[mt], 32);
      s2[mt] += __shfl_xor(s2[mt], 16); s2[mt] += __shfl_xor(s2[mt], 32);
    }
    float* st = (float*)&H1[0];
    if (lane < 16) {
#pragma unroll
      for (int mt = 0; mt < 4; ++mt) {
        st[wave * 128 + mt * 16 + lane] = s1[mt];
        st[wave * 128 + 64 + mt * 16 + lane] = s2[mt];
      }
    }
    __syncthreads();
    float mean[4], rstd[4];
#pragma unroll
    for (int mt = 0; mt < 4; ++mt) {
      float a = 0.f, q = 0.f;
#pragma unroll
      for (int w2 = 0; w2 < 8; ++w2) {
        a += st[w2 * 128 + mt * 16 + rl];
        q += st[w2 * 128 + 64 + mt * 16 + rl];
      }
      mean[mt] = a * (1.f / 256.f);
      float var = q * (1.f / 256.f) - mean[mt] * mean[mt];
      rstd[mt] = rsqrtf(fmaxf(var, 0.f) + 1e-5f);
    }
#pragma unroll
    for (int nf = 0; nf < 2; ++nf) {
      const int col = wave * 32 + nf * 16 + c4;
      const f32x4 sc4 = ld_bf4(lnsc + b * lnstride + col);
      const f32x4 sh4 = ld_bf4(lnsh + b * lnstride + col);
#pragma unroll
      for (int mt = 0; mt < 4; ++mt) {
        const long row = b * 64 + mt * 16 + rl;
        ushort4 xo;
        xo.x = f2b(acc[mt][nf][0]); xo.y = f2b(acc[mt][nf][1]);
        xo.z = f2b(acc[mt][nf][2]); xo.w = f2b(acc[mt][nf][3]);
        *(ushort4*)(xout + row * 256 + col) = xo;
        f32x4 h = (acc[mt][nf] - mean[mt]) * rstd[mt] * (1.f + sc4) + sh4;
        ushort4 o;
        o.x = f2b(h[0]); o.y = f2b(h[1]); o.z = f2b(h[2]); o.w = f2b(h[3]);
        *(ushort4*)(hout + row * 256 + col) = o;
      }
    }
    __syncthreads();  // stats reads done before next elem's epilogue-A overwrites H1
  }
}

// ---------------- fused attention: per (b, head-pair) block, wave=head ----------------
__global__ __launch_bounds__(128)
void attn_kernel(const u16* __restrict__ qkv, u16* __restrict__ out) {
  __shared__ __align__(16) u16 vt_s[2][64 * 72];
  __shared__ __align__(16) u16 p_s[2][64 * 72];
  const int lane = threadIdx.x & 63;
  const int wave = threadIdx.x >> 6;
  const long b = blockIdx.x >> 1;
  const int h = ((blockIdx.x & 1) << 1) | wave;
  u16* vt = vt_s[wave];
  u16* pl = p_s[wave];
  const u16* base = qkv + b * (64 * 768);
#pragma unroll
  for (int it = 0; it < 8; ++it) {
    int chunk = it * 64 + lane;
    int t = chunk >> 3, dhb = (chunk & 7) << 3;
    union { uint4 u; u16 s[8]; } uv;
    uv.u = *(const uint4*)(base + t * 768 + 512 + h * 64 + dhb);
#pragma unroll
    for (int j = 0; j < 8; ++j) vt[(dhb + j) * 72 + t] = uv.s[j];
  }
  const u16* qb = base + h * 64;
  const u16* kb = base + 256 + h * 64;
  f32x4 sacc[4][4] = {};
#pragma unroll
  for (int kt = 0; kt < 2; ++kt) {
    bf16x8 qa[4], kv[4];
#pragma unroll
    for (int mt = 0; mt < 4; ++mt)
      qa[mt] = ldb8(qb + ((lane & 15) + mt * 16) * 768 + kt * 32 + ((lane >> 4) << 3));
#pragma unroll
    for (int nt = 0; nt < 4; ++nt)
      kv[nt] = ldb8(kb + ((lane & 15) + nt * 16) * 768 + kt * 32 + ((lane >> 4) << 3));
#pragma unroll
    for (int mt = 0; mt < 4; ++mt)
#pragma unroll
      for (int nt = 0; nt < 4; ++nt)
        sacc[mt][nt] = __builtin_amdgcn_mfma_f32_16x16x32_bf16(qa[mt], kv[nt], sacc[mt][nt], 0, 0, 0);
  }
  const float scale = 0.125f;
#pragma unroll
  for (int mt = 0; mt < 4; ++mt) {
#pragma unroll
    for (int r = 0; r < 4; ++r) {
      float mx = fmaxf(fmaxf(sacc[mt][0][r], sacc[mt][1][r]), fmaxf(sacc[mt][2][r], sacc[mt][3][r]));
#pragma unroll
      for (int m = 1; m <= 8; m <<= 1) mx = fmaxf(mx, __shfl_xor(mx, m));
      float p[4];
      float sum = 0.f;
#pragma unroll
      for (int nt = 0; nt < 4; ++nt) { p[nt] = __expf((sacc[mt][nt][r] - mx) * scale); sum += p[nt]; }
#pragma unroll
      for (int m = 1; m <= 8; m <<= 1) sum += __shfl_xor(sum, m);
      const float rinv = 1.f / sum;
      const int s = mt * 16 + ((lane >> 4) << 2) + r;
#pragma unroll
      for (int nt = 0; nt < 4; ++nt) pl[s * 72 + nt * 16 + (lane & 15)] = f2b(p[nt] * rinv);
    }
  }
  __syncthreads();
  f32x4 oacc[4][4] = {};
#pragma unroll
  for (int kt = 0; kt < 2; ++kt) {
    bf16x8 pa[4], vv[4];
#pragma unroll
    for (int mt = 0; mt < 4; ++mt)
      pa[mt] = ldb8(pl + ((lane & 15) + mt * 16) * 72 + kt * 32 + ((lane >> 4) << 3));
#pragma unroll
    for (int nt = 0; nt < 4; ++nt)
      vv[nt] = ldb8(vt + ((lane & 15) + nt * 16) * 72 + kt * 32 + ((lane >> 4) << 3));
#pragma unroll
    for (int mt = 0; mt < 4; ++mt)
#pragma unroll
      for (int nt = 0; nt < 4; ++nt)
        oacc[mt][nt] = __builtin_amdgcn_mfma_f32_16x16x32_bf16(vv[nt], pa[mt], oacc[mt][nt], 0, 0, 0);
  }
  u16* ob = out + b * (64 * 256) + h * 64;
#pragma unroll
  for (int mt = 0; mt < 4; ++mt)
#pragma unroll
    for (int nt = 0; nt < 4; ++nt) {
      const int s = mt * 16 + (lane & 15);
      const int d4 = nt * 16 + ((lane >> 4) << 2);
      ushort4 o;
      o.x = f2b(oacc[mt][nt][0]); o.y = f2b(oacc[mt][nt][1]);
      o.z = f2b(oacc[mt][nt][2]); o.w = f2b(oacc[mt][nt][3]);
      *(ushort4*)(ob + s * 256 + d4) = o;
    }
}

extern "C" void kernel_launch(void* const* d_in, const int* in_sizes, int n_in,
                              void* d_out, int out_size, void* d_ws, size_t ws_size,
                              hipStream_t stream) {
  (void)in_sizes; (void)n_in; (void)out_size; (void)ws_size;
  const int B = 4096, L = 6;
  const long BSr = (long)B * 64;

  const float* x_t = (const float*)d_in[0];
  const int* tvec = (const int*)d_in[1];
  const float* backbone = (const float*)d_in[2];
  const float* emb = (const float*)d_in[3];
  const float* te_w1 = (const float*)d_in[4];
  const float* te_b1 = (const float*)d_in[5];
  const float* te_w2 = (const float*)d_in[6];
  const float* te_b2 = (const float*)d_in[7];
  const float* cp_w1 = (const float*)d_in[8];
  const float* cp_b1 = (const float*)d_in[9];
  const float* cp_w2 = (const float*)d_in[10];
  const float* cp_b2 = (const float*)d_in[11];
  const float* adaln_w = (const float*)d_in[12];
  const float* adaln_b = (const float*)d_in[13];
  const float* qkv_w = (const float*)d_in[14];
  const float* qkv_b = (const float*)d_in[15];
  const float* op_w = (const float*)d_in[16];
  const float* op_b = (const float*)d_in[17];
  const float* ffn_w1 = (const float*)d_in[18];
  const float* ffn_b1 = (const float*)d_in[19];
  const float* ffn_w2 = (const float*)d_in[20];
  const float* ffn_b2 = (const float*)d_in[21];
  const float* fa_w = (const float*)d_in[22];
  const float* fa_b = (const float*)d_in[23];
  const float* fp_w = (const float*)d_in[24];
  const float* fp_b = (const float*)d_in[25];

  char* w = (char*)d_ws;
  auto alloc = [&](size_t bytes) { char* p = w; w += (bytes + 255) & ~(size_t)255; return p; };
  u16* WT_cp1 = (u16*)alloc(256L * 512 * 2);
  u16* WT_cp2 = (u16*)alloc(256L * 256 * 2);
  u16* WT_adaln = (u16*)alloc(6L * 1536 * 256 * 2);  // = [9216][256] B^T
  u16* WT_qkv = (u16*)alloc(6L * 768 * 256 * 2);
  u16* WT_op = (u16*)alloc(6L * 256 * 256 * 2);
  u16* WT_f1 = (u16*)alloc(6L * 512 * 256 * 2);
  u16* WT_f2 = (u16*)alloc(6L * 256 * 512 * 2);
  u16* WT_fa = (u16*)alloc(512L * 256 * 2);
  u16* WT_fp = (u16*)alloc(256L * 256 * 2);
  float* te_tab = (float*)alloc(21L * 256 * 4);
  u16* cond = (u16*)alloc(4096L * 512 * 2);
  u16* c1 = (u16*)alloc(4096L * 256 * 2);
  u16* mc = (u16*)alloc(4096L * 256 * 2);
  u16* modb6 = (u16*)alloc(4096L * 9216 * 2);  // batch-major [4096][6*1536]
  u16* famod = (u16*)alloc(4096L * 512 * 2);
  u16* hbuf = (u16*)alloc(BSr * 256 * 2);
  u16* qkvbuf = (u16*)alloc(BSr * 768 * 2);
  u16* xbuf = (u16*)d_out;  // bf16 residual stream in d_out storage

  transpose_w<<<dim3(4, 8, 1), 256, 0, stream>>>(cp_w1, WT_cp1, 512, 256);
  transpose_w<<<dim3(4, 4, 1), 256, 0, stream>>>(cp_w2, WT_cp2, 256, 256);
  transpose_w<<<dim3(24, 4, 6), 256, 0, stream>>>(adaln_w, WT_adaln, 256, 1536);
  transpose_w<<<dim3(12, 4, 6), 256, 0, stream>>>(qkv_w, WT_qkv, 256, 768);
  transpose_w<<<dim3(4, 4, 6), 256, 0, stream>>>(op_w, WT_op, 256, 256);
  transpose_w<<<dim3(8, 4, 6), 256, 0, stream>>>(ffn_w1, WT_f1, 256, 512);
  transpose_w<<<dim3(4, 8, 6), 256, 0, stream>>>(ffn_w2, WT_f2, 512, 256);
  transpose_w<<<dim3(8, 4, 1), 256, 0, stream>>>(fa_w, WT_fa, 256, 512);
  transpose_w<<<dim3(4, 4, 1), 256, 0, stream>>>(fp_w, WT_fp, 256, 256);

  te_table_kernel<<<21, 1024, 0, stream>>>(emb, te_w1, te_b1, te_w2, te_b2, te_tab);
  cond_mean_kernel<<<4096, 256, 0, stream>>>(backbone, cond);

  gemm_bt<1><<<dim3(2, 32), 256, 0, stream>>>(cond, WT_cp1, cp_b1, c1, nullptr, nullptr, 4096, 256, 512);
  gemm_bt<4><<<dim3(2, 32), 256, 0, stream>>>(c1, WT_cp2, cp_b2, mc, tvec, te_tab, 4096, 256, 256);
  gemm_bt<0><<<dim3(4, 32), 256, 0, stream>>>(mc, WT_fa, fa_b, famod, nullptr, nullptr, 4096, 512, 256);
  // single adaLN GEMM over all 6 layers: N = 6*1536 = 9216 (2304 blocks)
  gemm_bt<0><<<dim3(72, 32), 256, 0, stream>>>(mc, WT_adaln, adaln_b, modb6, nullptr, nullptr, 4096, 9216, 256);

  // layer-0 input LN (sh1/sc1)
  ln_mod<<<BSr / 4, 256, 0, stream>>>(x_t, modb6, 9216, 0, 256, hbuf);

  for (int l = 0; l < L; ++l) {
    const u16* mb = modb6 + (long)l * 1536;  // batch-major: row stride 9216
    // QKV GEMM with XCD-aware swizzle (6 N-blocks sharing an A-tile -> same XCD)
    gemm_bt<0, true><<<dim3(6, BSr / 128), 256, 0, stream>>>(hbuf, WT_qkv + (long)l * 768 * 256, qkv_b + l * 768,
                                                             qkvbuf, nullptr, nullptr, (int)BSr, 768, 256);
    attn_kernel<<<B * 2, 128, 0, stream>>>(qkvbuf, hbuf);
    // x = xin + g1*(attn_out @ Wop + b); h = LN(x)*(1+sc2)+sh2
    if (l == 0)
      gemm_ln<256, true><<<BSr / 64, 256, 0, stream>>>(hbuf, WT_op, op_b, x_t, mb + 512, 9216,
                                                       mb + 768, mb + 1024, 9216, xbuf, hbuf);
    else
      gemm_ln<256, false><<<BSr / 64, 256, 0, stream>>>(hbuf, WT_op + (long)l * 256 * 256, op_b + l * 256,
                                                        xbuf, mb + 512, 9216, mb + 768, mb + 1024, 9216, xbuf, hbuf);
    // fused FFN1+FFN2 + residual + next-layer LN (2 elems per block, pipelined)
    const u16* nsh = (l < 5) ? (mb + 1536) : famod;
    const u16* nsc = (l < 5) ? (mb + 1536 + 256) : (famod + 256);
    const int nstride = (l < 5) ? 9216 : 512;
    ffn_fused<<<BSr / 128, 512, 0, stream>>>(hbuf, WT_f1 + (long)l * 512 * 256, ffn_b1 + l * 512,
                                             WT_f2 + (long)l * 256 * 512, ffn_b2 + l * 256,
                                             xbuf, mb + 1280, 9216, nsh, nsc, nstride, xbuf, hbuf);
  }
  gemm_bt<3><<<dim3(2, BSr / 128), 256, 0, stream>>>(hbuf, WT_fp, fp_b, d_out, nullptr, nullptr, (int)BSr, 256, 256);
}

// Round 22
// 6218.835 us; speedup vs baseline: 1.0494x; 1.0010x over previous
//
#include <hip/hip_runtime.h>

typedef unsigned short u16;
typedef float f32x4 __attribute__((ext_vector_type(4)));
typedef __bf16 bf16x8 __attribute__((ext_vector_type(8)));

__device__ __forceinline__ u16 f2b(float f) {
  unsigned u = __builtin_bit_cast(unsigned, f);
  u += 0x7FFF + ((u >> 16) & 1);
  return (u16)(u >> 16);
}

__device__ __forceinline__ float b2f(u16 v) {
  unsigned u = (unsigned)v << 16;
  return __builtin_bit_cast(float, u);
}

__device__ __forceinline__ f32x4 ld_bf4(const u16* p) {
  ushort4 v = *(const ushort4*)p;
  f32x4 r;
  r[0] = b2f(v.x); r[1] = b2f(v.y); r[2] = b2f(v.z); r[3] = b2f(v.w);
  return r;
}

// mish(x) = x * tanh(softplus(x)) = x * (e^2+2e)/(e^2+2e+2), e = exp(x)
__device__ __forceinline__ float mishf(float x) {
  float e = __expf(fminf(x, 20.f));
  float n = e * (e + 2.f);
  return x * __fdividef(n, n + 2.f);
}

__device__ __forceinline__ void gl_lds16(const void* g, void* l) {
  __builtin_amdgcn_global_load_lds((__attribute__((address_space(1))) void*)g,
                                   (__attribute__((address_space(3))) void*)l, 16, 0, 0);
}

__device__ __forceinline__ bf16x8 ldb8(const u16* p) {
  return __builtin_bit_cast(bf16x8, *(const uint4*)p);
}

// ---------------- weight transpose f32[K,N] -> bf16[N,K] ----------------
__global__ __launch_bounds__(256)
void transpose_w(const float* __restrict__ in, u16* __restrict__ out, int K, int N) {
  __shared__ float tl[64][65];
  const long zoff = (long)blockIdx.z * K * N;
  in += zoff; out += zoff;
  const int n0 = blockIdx.x * 64, k0 = blockIdx.y * 64;
  const int c = threadIdx.x & 63, r0 = threadIdx.x >> 6;
#pragma unroll
  for (int i = 0; i < 16; ++i) {
    int r = i * 4 + r0;
    tl[r][c] = in[(long)(k0 + r) * N + n0 + c];
  }
  __syncthreads();
#pragma unroll
  for (int i = 0; i < 16; ++i) {
    int r = i * 4 + r0;
    out[(long)(n0 + r) * K + k0 + c] = f2b(tl[c][r]);
  }
}

// ---------------- timestep-embedding MLP table (21 rows) ----------------
__global__ __launch_bounds__(1024)
void te_table_kernel(const float* __restrict__ emb, const float* __restrict__ w1,
                     const float* __restrict__ b1, const float* __restrict__ w2,
                     const float* __restrict__ b2, float* __restrict__ table) {
  __shared__ float te[256];
  __shared__ float h1[1024];
  __shared__ float red[1024];
  const int tt = blockIdx.x, tid = threadIdx.x;
  if (tid < 256) te[tid] = emb[tt * 256 + tid];
  __syncthreads();
  float a = b1[tid];
#pragma unroll 8
  for (int k = 0; k < 256; ++k) a += te[k] * w1[k * 1024 + tid];
  h1[tid] = mishf(a);
  __syncthreads();
  const int j = tid & 255, kq = tid >> 8;
  float a2 = 0.f;
#pragma unroll 8
  for (int k = kq * 256; k < kq * 256 + 256; ++k) a2 += h1[k] * w2[k * 256 + j];
  red[tid] = a2;
  __syncthreads();
  if (tid < 256)
    table[tt * 256 + tid] = b2[tid] + red[tid] + red[tid + 256] + red[tid + 512] + red[tid + 768];
}

// ---------------- cond = mean over S, written bf16 ----------------
__global__ __launch_bounds__(256)
void cond_mean_kernel(const float* __restrict__ bb, u16* __restrict__ cond) {
  const int b = blockIdx.x, tid = threadIdx.x;
  const float* p = bb + (long)b * 64 * 512;
  for (int d = tid; d < 512; d += 256) {
    float s = 0.f;
#pragma unroll
    for (int t = 0; t < 64; ++t) s += p[t * 512 + d];
    cond[b * 512 + d] = f2b(s * (1.f / 64.f));
  }
}

// ---------------- LayerNorm + adaLN modulate -> bf16 (layer-0 input; mod is bf16) ----------------
__global__ __launch_bounds__(256)
void ln_mod(const float* __restrict__ x, const u16* __restrict__ modb,
            int mstride, int shoff, int scoff, u16* __restrict__ out) {
  const int lane = threadIdx.x & 63;
  const long row = (long)blockIdx.x * 4 + (threadIdx.x >> 6);
  const float4 xv = *(const float4*)(x + row * 256 + lane * 4);
  float s1 = xv.x + xv.y + xv.z + xv.w;
  float s2 = xv.x * xv.x + xv.y * xv.y + xv.z * xv.z + xv.w * xv.w;
#pragma unroll
  for (int m = 1; m < 64; m <<= 1) { s1 += __shfl_xor(s1, m); s2 += __shfl_xor(s2, m); }
  const float mean = s1 * (1.f / 256.f);
  float var = s2 * (1.f / 256.f) - mean * mean;
  const float rstd = rsqrtf(fmaxf(var, 0.f) + 1e-5f);
  const long b = row >> 6;
  const f32x4 sc = ld_bf4(modb + b * mstride + scoff + lane * 4);
  const f32x4 sh = ld_bf4(modb + b * mstride + shoff + lane * 4);
  ushort4 o;
  o.x = f2b((xv.x - mean) * rstd * (1.f + sc[0]) + sh[0]);
  o.y = f2b((xv.y - mean) * rstd * (1.f + sc[1]) + sh[1]);
  o.z = f2b((xv.z - mean) * rstd * (1.f + sc[2]) + sh[2]);
  o.w = f2b((xv.w - mean) * rstd * (1.f + sc[3]) + sh[3]);
  *(ushort4*)(out + row * 256 + lane * 4) = o;
}

// ---------------- GEMM: C[M,N] = A[M,K](bf16) @ Bt[N,K]^T(bf16) + epilogue ----------------
// EPI 0: +bias -> bf16 | 1: mish(+bias) -> bf16 | 3: +bias -> f32
// EPI 4: mish(+bias + te_table[t[row]]) -> bf16
// XSWZ: XCD-aware remap so the gridDim.x blocks sharing one A-tile land on one XCD
// (bijective for gridDim.y % 8 == 0; affects locality only, not correctness).
template <int EPI, bool XSWZ = false>
__global__ __launch_bounds__(256)
void gemm_bt(const u16* __restrict__ A, const u16* __restrict__ Bt,
             const float* __restrict__ bias, void* __restrict__ outp,
             const int* __restrict__ tvec, const float* __restrict__ tetab,
             int M, int N, int K) {
  __shared__ __align__(16) u16 As[2][128 * 64];
  __shared__ __align__(16) u16 Bs[2][128 * 64];
  const int tid = threadIdx.x;
  const int lane = tid & 63;
  const int wave = tid >> 6;
  const int wr = (wave >> 1) << 6;
  const int wc = (wave & 1) << 6;
  long tm, tn;
  if constexpr (XSWZ) {
    const int NX = gridDim.x;
    const int d = blockIdx.y * NX + blockIdx.x;
    const int r = d & 7, q = d >> 3;
    const int gq = q / NX, i = q % NX;
    tm = (long)(gq * 8 + r) * 128;
    tn = (long)i * 128;
  } else {
    tm = (long)blockIdx.y * 128;
    tn = (long)blockIdx.x * 128;
  }
  const u16* Ag = A + tm * K;
  const u16* Bg = Bt + tn * K;
  f32x4 acc[4][4] = {};
  const int kcb = lane >> 4;
  const int swz = lane & 7;
  const int NT = K >> 6;

  auto stage = [&](int t, int buf) {
    const int k0 = t << 6;
#pragma unroll
    for (int i = 0; i < 4; ++i) {
      int c = tid + (i << 8);
      int r = c >> 3;
      int sch = (c & 7) ^ (r & 7);
      gl_lds16(Ag + (long)r * K + k0 + (sch << 3), &As[buf][c << 3]);
    }
#pragma unroll
    for (int i = 0; i < 4; ++i) {
      int c = tid + (i << 8);
      int r = c >> 3;
      int sch = (c & 7) ^ (r & 7);
      gl_lds16(Bg + (long)r * K + k0 + (sch << 3), &Bs[buf][c << 3]);
    }
  };

  stage(0, 0);
  __syncthreads();
  int cur = 0;
  for (int t = 0; t < NT; ++t) {
    if (t + 1 < NT) stage(t + 1, cur ^ 1);
#pragma unroll
    for (int kt = 0; kt < 2; ++kt) {
      const int ko = ((kt * 4 + kcb) ^ swz) << 3;
      bf16x8 av[4], bv[4];
#pragma unroll
      for (int mt = 0; mt < 4; ++mt)
        av[mt] = ldb8(&As[cur][(wr + mt * 16 + (lane & 15)) * 64 + ko]);
#pragma unroll
      for (int nt = 0; nt < 4; ++nt)
        bv[nt] = ldb8(&Bs[cur][(wc + nt * 16 + (lane & 15)) * 64 + ko]);
#pragma unroll
      for (int mt = 0; mt < 4; ++mt)
#pragma unroll
        for (int nt = 0; nt < 4; ++nt)
          acc[mt][nt] = __builtin_amdgcn_mfma_f32_16x16x32_bf16(bv[nt], av[mt], acc[mt][nt], 0, 0, 0);
    }
    __syncthreads();
    cur ^= 1;
  }
  const int rl = lane & 15;
  const int c4 = (lane >> 4) << 2;
  f32x4 b4[4];
#pragma unroll
  for (int nt = 0; nt < 4; ++nt)
    b4[nt] = *(const f32x4*)(bias + (int)tn + wc + nt * 16 + c4);
#pragma unroll
  for (int mt = 0; mt < 4; ++mt) {
    const unsigned row = (unsigned)(tm + wr + mt * 16 + rl);
    const unsigned rb = row * (unsigned)N;
#pragma unroll
    for (int nt = 0; nt < 4; ++nt) {
      const unsigned col = (unsigned)tn + wc + nt * 16 + c4;
      f32x4 v = acc[mt][nt] + b4[nt];
      if constexpr (EPI == 0) {
        ushort4 o;
        o.x = f2b(v[0]); o.y = f2b(v[1]); o.z = f2b(v[2]); o.w = f2b(v[3]);
        *(ushort4*)((u16*)outp + rb + col) = o;
      } else if constexpr (EPI == 1) {
        ushort4 o;
        o.x = f2b(mishf(v[0])); o.y = f2b(mishf(v[1]));
        o.z = f2b(mishf(v[2])); o.w = f2b(mishf(v[3]));
        *(ushort4*)((u16*)outp + rb + col) = o;
      } else if constexpr (EPI == 3) {
        *(f32x4*)((float*)outp + rb + col) = v;
      } else {
        const f32x4 te = *(const f32x4*)(tetab + tvec[row] * 256 + col);
        ushort4 o;
        o.x = f2b(mishf(v[0] + te[0])); o.y = f2b(mishf(v[1] + te[1]));
        o.z = f2b(mishf(v[2] + te[2])); o.w = f2b(mishf(v[3] + te[3]));
        *(ushort4*)((u16*)outp + rb + col) = o;
      }
    }
  }
}

// ---------------- GEMM (N=256 full rows) + residual + LayerNorm + modulate ----------------
// (op-projection stage) 256 thr / 4 waves; block = 64 rows. Residual bf16; mods bf16.
template <int K, bool XF32>
__global__ __launch_bounds__(256)
void gemm_ln(const u16* __restrict__ A, const u16* __restrict__ Bt,
             const float* __restrict__ bias, const void* __restrict__ xin,
             const u16* __restrict__ gptr, int gstride,
             const u16* __restrict__ lnsh, const u16* __restrict__ lnsc, int lnstride,
             u16* __restrict__ xout, u16* __restrict__ hout) {
  __shared__ __align__(16) u16 As[2][64 * 64];
  __shared__ __align__(16) u16 Bs[2][256 * 64];
  const int tid = threadIdx.x, lane = tid & 63, wave = tid >> 6;
  const int wc = wave << 6;
  const long tm = (long)blockIdx.x * 64;
  const u16* Ag = A + tm * K;
  const int rl = lane & 15;
  const int c4 = (lane >> 4) << 2;
  const int swz = lane & 7;
  const int NT = K >> 6;

  auto stage = [&](int t, int buf) {
    const int k0 = t << 6;
#pragma unroll
    for (int i = 0; i < 2; ++i) {
      int c = tid + (i << 8);
      int r = c >> 3;
      int sch = (c & 7) ^ (r & 7);
      gl_lds16(Ag + (long)r * K + k0 + (sch << 3), &As[buf][c << 3]);
    }
#pragma unroll
    for (int i = 0; i < 8; ++i) {
      int c = tid + (i << 8);
      int r = c >> 3;
      int sch = (c & 7) ^ (r & 7);
      gl_lds16(Bt + (long)r * K + k0 + (sch << 3), &Bs[buf][c << 3]);
    }
  };

  stage(0, 0);
  __syncthreads();

  f32x4 acc[4][4] = {};
  int cur = 0;
  for (int t = 0; t < NT; ++t) {
    if (t + 1 < NT) stage(t + 1, cur ^ 1);
#pragma unroll
    for (int kt = 0; kt < 2; ++kt) {
      const int ko = ((kt * 4 + (lane >> 4)) ^ swz) << 3;
      bf16x8 av[4], bv[4];
#pragma unroll
      for (int mt = 0; mt < 4; ++mt)
        av[mt] = ldb8(&As[cur][(mt * 16 + rl) * 64 + ko]);
#pragma unroll
      for (int nt = 0; nt < 4; ++nt)
        bv[nt] = ldb8(&Bs[cur][(wc + nt * 16 + rl) * 64 + ko]);
#pragma unroll
      for (int mt = 0; mt < 4; ++mt)
#pragma unroll
        for (int nt = 0; nt < 4; ++nt)
          acc[mt][nt] = __builtin_amdgcn_mfma_f32_16x16x32_bf16(bv[nt], av[mt], acc[mt][nt], 0, 0, 0);
    }
    __syncthreads();
    cur ^= 1;
  }

  const long b = blockIdx.x;
  float s1[4] = {}, s2[4] = {};
#pragma unroll
  for (int nt = 0; nt < 4; ++nt) {
    const int col = wc + nt * 16 + c4;
    const f32x4 b4 = *(const f32x4*)(bias + col);
    const f32x4 g4 = ld_bf4(gptr + b * gstride + col);
#pragma unroll
    for (int mt = 0; mt < 4; ++mt) {
      const long row = tm + mt * 16 + rl;
      f32x4 x;
      if constexpr (XF32) x = *(const f32x4*)((const float*)xin + row * 256 + col);
      else x = ld_bf4((const u16*)xin + row * 256 + col);
      f32x4 xn = x + g4 * (acc[mt][nt] + b4);
      acc[mt][nt] = xn;
      s1[mt] += xn[0] + xn[1] + xn[2] + xn[3];
      s2[mt] += xn[0] * xn[0] + xn[1] * xn[1] + xn[2] * xn[2] + xn[3] * xn[3];
    }
  }
#pragma unroll
  for (int mt = 0; mt < 4; ++mt) {
    s1[mt] += __shfl_xor(s1[mt], 16); s1[mt] += __shfl_xor(s1[mt], 32);
    s2[mt] += __shfl_xor(s2[mt], 16); s2[mt] += __shfl_xor(s2[mt], 32);
  }
  float* st = (float*)&As[0][0];
  if (lane < 16) {
#pragma unroll
    for (int mt = 0; mt < 4; ++mt) {
      st[wave * 128 + mt * 16 + lane] = s1[mt];
      st[wave * 128 + 64 + mt * 16 + lane] = s2[mt];
    }
  }
  __syncthreads();
  float mean[4], rstd[4];
#pragma unroll
  for (int mt = 0; mt < 4; ++mt) {
    float a = 0.f, q = 0.f;
#pragma unroll
    for (int w2 = 0; w2 < 4; ++w2) {
      a += st[w2 * 128 + mt * 16 + rl];
      q += st[w2 * 128 + 64 + mt * 16 + rl];
    }
    mean[mt] = a * (1.f / 256.f);
    float var = q * (1.f / 256.f) - mean[mt] * mean[mt];
    rstd[mt] = rsqrtf(fmaxf(var, 0.f) + 1e-5f);
  }
#pragma unroll
  for (int nt = 0; nt < 4; ++nt) {
    const int col = wc + nt * 16 + c4;
    const f32x4 sc4 = ld_bf4(lnsc + b * lnstride + col);
    const f32x4 sh4 = ld_bf4(lnsh + b * lnstride + col);
#pragma unroll
    for (int mt = 0; mt < 4; ++mt) {
      const long row = tm + mt * 16 + rl;
      ushort4 xo;
      xo.x = f2b(acc[mt][nt][0]); xo.y = f2b(acc[mt][nt][1]);
      xo.z = f2b(acc[mt][nt][2]); xo.w = f2b(acc[mt][nt][3]);
      *(ushort4*)(xout + row * 256 + col) = xo;
      f32x4 h = (acc[mt][nt] - mean[mt]) * rstd[mt] * (1.f + sc4) + sh4;
      ushort4 o;
      o.x = f2b(h[0]); o.y = f2b(h[1]); o.z = f2b(h[2]); o.w = f2b(h[3]);
      *(ushort4*)(hout + row * 256 + col) = o;
    }
  }
}

// ---------------- fused FFN: x=x+g2*(mish(xln@W1^T+b1)@W2^T+b2); h=LN(x)*(1+sc)+sh ----------------
// Block processes TWO batch elems, software-pipelined (R15-proven). LDS 160KB (1 block/CU).
__global__ __launch_bounds__(512)
void ffn_fused(const u16* __restrict__ xln, const u16* __restrict__ W1t,
               const float* __restrict__ b1, const u16* __restrict__ W2t,
               const float* __restrict__ b2, const u16* __restrict__ xres,
               const u16* __restrict__ gptr, int gstride,
               const u16* __restrict__ lnsh, const u16* __restrict__ lnsc, int lnstride,
               u16* __restrict__ xout, u16* __restrict__ hout) {
  __shared__ __align__(16) u16 Ax[64 * 256];
  __shared__ __align__(16) u16 Ws[2][256 * 64];
  __shared__ __align__(16) u16 H1[64 * 512];
  const int tid = threadIdx.x, lane = tid & 63, wave = tid >> 6;
  const long b0 = (long)blockIdx.x * 2;
  const int rl = lane & 15;
  const int c4 = (lane >> 4) << 2;
  const int kq = lane >> 4;

  auto stageAx = [&](long b) {
    const u16* src = xln + b * (64 * 256);
#pragma unroll
    for (int i = 0; i < 4; ++i) {
      int c = tid + (i << 9);
      int r = c >> 5, cc = c & 31;
      int sch = (cc & ~7) | ((cc & 7) ^ (r & 7));
      gl_lds16(src + r * 256 + (sch << 3), &Ax[c << 3]);
    }
  };
  auto stageW = [&](const u16* Wsrc, int Kw, int R0, int k0, int buf) {
#pragma unroll
    for (int i = 0; i < 4; ++i) {
      int c = tid + (i << 9);
      int r = c >> 3;
      int sch = (c & 7) ^ (r & 7);
      gl_lds16(Wsrc + (long)(R0 + r) * Kw + k0 + (sch << 3), &Ws[buf][c << 3]);
    }
  };

  stageAx(b0);
  stageW(W1t, 256, 0, 0, 0);
  __syncthreads();
  int cur = 0;

  for (int e = 0; e < 2; ++e) {
    const long b = b0 + e;
    // ---- phase A: h1 = mish(xln @ W1t^T + b1), two 256-col halves ----
    for (int nh = 0; nh < 2; ++nh) {
      f32x4 acc[4][2] = {};
      for (int t = 0; t < 4; ++t) {
        int s = nh * 4 + t;
        if (s < 7) stageW(W1t, 256, ((s + 1) >> 2) * 256, ((s + 1) & 3) * 64, cur ^ 1);
        else stageW(W2t, 512, 0, 0, cur ^ 1);  // prefetch phase-B tile 0
#pragma unroll
        for (int kt = 0; kt < 2; ++kt) {
          bf16x8 av[4], bv[2];
#pragma unroll
          for (int mt = 0; mt < 4; ++mt) {
            int r = mt * 16 + rl;
            int kc = t * 8 + kt * 4 + kq;
            int slot = (kc & ~7) | ((kc & 7) ^ (r & 7));
            av[mt] = ldb8(&Ax[r * 256 + (slot << 3)]);
          }
#pragma unroll
          for (int nf = 0; nf < 2; ++nf) {
            int wr_ = wave * 32 + nf * 16 + rl;
            int slot = (kt * 4 + kq) ^ (wr_ & 7);
            bv[nf] = ldb8(&Ws[cur][wr_ * 64 + (slot << 3)]);
          }
          __builtin_amdgcn_s_setprio(1);
#pragma unroll
          for (int mt = 0; mt < 4; ++mt)
#pragma unroll
            for (int nf = 0; nf < 2; ++nf)
              acc[mt][nf] = __builtin_amdgcn_mfma_f32_16x16x32_bf16(bv[nf], av[mt], acc[mt][nf], 0, 0, 0);
          __builtin_amdgcn_s_setprio(0);
        }
        __syncthreads();
        cur ^= 1;
      }
      // epilogue A: mish -> H1 (swizzled ds_write)
#pragma unroll
      for (int nf = 0; nf < 2; ++nf) {
        const int col = nh * 256 + wave * 32 + nf * 16 + c4;
        const f32x4 bb = *(const f32x4*)(b1 + col);
        const int c8 = col >> 3;
        const int sub = (col & 7) << 1;
#pragma unroll
        for (int mt = 0; mt < 4; ++mt) {
          const int r = mt * 16 + rl;
          f32x4 v = acc[mt][nf] + bb;
          ushort4 o;
          o.x = f2b(mishf(v[0])); o.y = f2b(mishf(v[1]));
          o.z = f2b(mishf(v[2])); o.w = f2b(mishf(v[3]));
          int slot = (c8 & ~7) | ((c8 & 7) ^ (r & 7));
          *(ushort4*)((char*)H1 + r * 1024 + (slot << 4) + sub) = o;
        }
      }
    }
    __syncthreads();  // H1 visible; W2 tile 0 staged; all Ax reads complete

    // ---- phase B: out = h1 @ W2t^T + b2; residual + LN ----
    f32x4 acc[4][2] = {};
    for (int t = 0; t < 8; ++t) {
      if (t < 7) stageW(W2t, 512, 0, (t + 1) * 64, cur ^ 1);
      else if (e == 0) stageW(W1t, 256, 0, 0, cur ^ 1);  // next elem's W1 tile 0
      if (t == 0 && e == 0) stageAx(b0 + 1);             // next elem's x (Ax dead)
#pragma unroll
      for (int kt = 0; kt < 2; ++kt) {
        bf16x8 av[4], bv[2];
#pragma unroll
        for (int mt = 0; mt < 4; ++mt) {
          int r = mt * 16 + rl;
          int kc = t * 8 + kt * 4 + kq;
          int slot = (kc & ~7) | ((kc & 7) ^ (r & 7));
          av[mt] = ldb8((const u16*)((const char*)H1 + r * 1024 + (slot << 4)));
        }
#pragma unroll
        for (int nf = 0; nf < 2; ++nf) {
          int wr_ = wave * 32 + nf * 16 + rl;
          int slot = (kt * 4 + kq) ^ (wr_ & 7);
          bv[nf] = ldb8(&Ws[cur][wr_ * 64 + (slot << 3)]);
        }
        __builtin_amdgcn_s_setprio(1);
#pragma unroll
        for (int mt = 0; mt < 4; ++mt)
#pragma unroll
          for (int nf = 0; nf < 2; ++nf)
            acc[mt][nf] = __builtin_amdgcn_mfma_f32_16x16x32_bf16(bv[nf], av[mt], acc[mt][nf], 0, 0, 0);
        __builtin_amdgcn_s_setprio(0);
      }
      __syncthreads();
      cur ^= 1;
    }
    // residual + row stats (wave's 32-col strip); stats scratch in H1 (dead after phase B)
    float s1[4] = {}, s2[4] = {};
#pragma unroll
    for (int nf = 0; nf < 2; ++nf) {
      const int col = wave * 32 + nf * 16 + c4;
      const f32x4 bb = *(const f32x4*)(b2 + col);
      const f32x4 g4 = ld_bf4(gptr + b * gstride + col);
#pragma unroll
      for (int mt = 0; mt < 4; ++mt) {
        const long row = b * 64 + mt * 16 + rl;
        f32x4 x = ld_bf4(xres + row * 256 + col);
        f32x4 xn = x + g4 * (acc[mt][nf] + bb);
        acc[mt][nf] = xn;
        s1[mt] += xn[0] + xn[1] + xn[2] + xn[3];
        s2[mt] += xn[0] * xn[0] + xn[1] * xn[1] + xn[2] * xn[2] + xn[3] * xn[3];
      }
    }
#pragma unroll
    for (int mt = 0; mt < 4; ++mt) {
      s1[mt] += __shfl_xor(s1[mt], 16); s1[mt] += __shfl_xor(s1[mt], 32);
      s2[mt] += __shfl_xor(s2[mt], 16); s2[mt] += __shfl_xor(s2[mt], 32);
    }
    float* st = (float*)&H1[0];
    if (lane < 16) {
#pragma unroll
      for (int mt = 0; mt < 4; ++mt) {
        st[wave * 128 + mt * 16 + lane] = s1[mt];
        st[wave * 128 + 64 + mt * 16 + lane] = s2[mt];
      }
    }
    __syncthreads();
    float mean[4], rstd[4];
#pragma unroll
    for (int mt = 0; mt < 4; ++mt) {
      float a = 0.f, q = 0.f;
#pragma unroll
      for (int w2 = 0; w2 < 8; ++w2) {
        a += st[w2 * 128 + mt * 16 + rl];
        q += st[w2 * 128 + 64 + mt * 16 + rl];
      }
      mean[mt] = a * (1.f / 256.f);
      float var = q * (1.f / 256.f) - mean[mt] * mean[mt];
      rstd[mt] = rsqrtf(fmaxf(var, 0.f) + 1e-5f);
    }
#pragma unroll
    for (int nf = 0; nf < 2; ++nf) {
      const int col = wave * 32 + nf * 16 + c4;
      const f32x4 sc4 = ld_bf4(lnsc + b * lnstride + col);
      const f32x4 sh4 = ld_bf4(lnsh + b * lnstride + col);
#pragma unroll
      for (int mt = 0; mt < 4; ++mt) {
        const long row = b * 64 + mt * 16 + rl;
        ushort4 xo;
        xo.x = f2b(acc[mt][nf][0]); xo.y = f2b(acc[mt][nf][1]);
        xo.z = f2b(acc[mt][nf][2]); xo.w = f2b(acc[mt][nf][3]);
        *(ushort4*)(xout + row * 256 + col) = xo;
        f32x4 h = (acc[mt][nf] - mean[mt]) * rstd[mt] * (1.f + sc4) + sh4;
        ushort4 o;
        o.x = f2b(h[0]); o.y = f2b(h[1]); o.z = f2b(h[2]); o.w = f2b(h[3]);
        *(ushort4*)(hout + row * 256 + col) = o;
      }
    }
    __syncthreads();  // stats reads done before next elem's epilogue-A overwrites H1
  }
}

// ---------------- fused attention: per (b, head-pair) block, wave=head ----------------
__global__ __launch_bounds__(128)
void attn_kernel(const u16* __restrict__ qkv, u16* __restrict__ out) {
  __shared__ __align__(16) u16 vt_s[2][64 * 72];
  __shared__ __align__(16) u16 p_s[2][64 * 72];
  const int lane = threadIdx.x & 63;
  const int wave = threadIdx.x >> 6;
  const long b = blockIdx.x >> 1;
  const int h = ((blockIdx.x & 1) << 1) | wave;
  u16* vt = vt_s[wave];
  u16* pl = p_s[wave];
  const u16* base = qkv + b * (64 * 768);
#pragma unroll
  for (int it = 0; it < 8; ++it) {
    int chunk = it * 64 + lane;
    int t = chunk >> 3, dhb = (chunk & 7) << 3;
    union { uint4 u; u16 s[8]; } uv;
    uv.u = *(const uint4*)(base + t * 768 + 512 + h * 64 + dhb);
#pragma unroll
    for (int j = 0; j < 8; ++j) vt[(dhb + j) * 72 + t] = uv.s[j];
  }
  const u16* qb = base + h * 64;
  const u16* kb = base + 256 + h * 64;
  f32x4 sacc[4][4] = {};
#pragma unroll
  for (int kt = 0; kt < 2; ++kt) {
    bf16x8 qa[4], kv[4];
#pragma unroll
    for (int mt = 0; mt < 4; ++mt)
      qa[mt] = ldb8(qb + ((lane & 15) + mt * 16) * 768 + kt * 32 + ((lane >> 4) << 3));
#pragma unroll
    for (int nt = 0; nt < 4; ++nt)
      kv[nt] = ldb8(kb + ((lane & 15) + nt * 16) * 768 + kt * 32 + ((lane >> 4) << 3));
#pragma unroll
    for (int mt = 0; mt < 4; ++mt)
#pragma unroll
      for (int nt = 0; nt < 4; ++nt)
        sacc[mt][nt] = __builtin_amdgcn_mfma_f32_16x16x32_bf16(qa[mt], kv[nt], sacc[mt][nt], 0, 0, 0);
  }
  const float scale = 0.125f;
#pragma unroll
  for (int mt = 0; mt < 4; ++mt) {
#pragma unroll
    for (int r = 0; r < 4; ++r) {
      float mx = fmaxf(fmaxf(sacc[mt][0][r], sacc[mt][1][r]), fmaxf(sacc[mt][2][r], sacc[mt][3][r]));
#pragma unroll
      for (int m = 1; m <= 8; m <<= 1) mx = fmaxf(mx, __shfl_xor(mx, m));
      float p[4];
      float sum = 0.f;
#pragma unroll
      for (int nt = 0; nt < 4; ++nt) { p[nt] = __expf((sacc[mt][nt][r] - mx) * scale); sum += p[nt]; }
#pragma unroll
      for (int m = 1; m <= 8; m <<= 1) sum += __shfl_xor(sum, m);
      const float rinv = 1.f / sum;
      const int s = mt * 16 + ((lane >> 4) << 2) + r;
#pragma unroll
      for (int nt = 0; nt < 4; ++nt) pl[s * 72 + nt * 16 + (lane & 15)] = f2b(p[nt] * rinv);
    }
  }
  __syncthreads();
  f32x4 oacc[4][4] = {};
#pragma unroll
  for (int kt = 0; kt < 2; ++kt) {
    bf16x8 pa[4], vv[4];
#pragma unroll
    for (int mt = 0; mt < 4; ++mt)
      pa[mt] = ldb8(pl + ((lane & 15) + mt * 16) * 72 + kt * 32 + ((lane >> 4) << 3));
#pragma unroll
    for (int nt = 0; nt < 4; ++nt)
      vv[nt] = ldb8(vt + ((lane & 15) + nt * 16) * 72 + kt * 32 + ((lane >> 4) << 3));
#pragma unroll
    for (int mt = 0; mt < 4; ++mt)
#pragma unroll
      for (int nt = 0; nt < 4; ++nt)
        oacc[mt][nt] = __builtin_amdgcn_mfma_f32_16x16x32_bf16(vv[nt], pa[mt], oacc[mt][nt], 0, 0, 0);
  }
  u16* ob = out + b * (64 * 256) + h * 64;
#pragma unroll
  for (int mt = 0; mt < 4; ++mt)
#pragma unroll
    for (int nt = 0; nt < 4; ++nt) {
      const int s = mt * 16 + (lane & 15);
      const int d4 = nt * 16 + ((lane >> 4) << 2);
      ushort4 o;
      o.x = f2b(oacc[mt][nt][0]); o.y = f2b(oacc[mt][nt][1]);
      o.z = f2b(oacc[mt][nt][2]); o.w = f2b(oacc[mt][nt][3]);
      *(ushort4*)(ob + s * 256 + d4) = o;
    }
}

extern "C" void kernel_launch(void* const* d_in, const int* in_sizes, int n_in,
                              void* d_out, int out_size, void* d_ws, size_t ws_size,
                              hipStream_t stream) {
  (void)in_sizes; (void)n_in; (void)out_size; (void)ws_size;
  const int B = 4096, L = 6;
  const long BSr = (long)B * 64;

  const float* x_t = (const float*)d_in[0];
  const int* tvec = (const int*)d_in[1];
  const float* backbone = (const float*)d_in[2];
  const float* emb = (const float*)d_in[3];
  const float* te_w1 = (const float*)d_in[4];
  const float* te_b1 = (const float*)d_in[5];
  const float* te_w2 = (const float*)d_in[6];
  const float* te_b2 = (const float*)d_in[7];
  const float* cp_w1 = (const float*)d_in[8];
  const float* cp_b1 = (const float*)d_in[9];
  const float* cp_w2 = (const float*)d_in[10];
  const float* cp_b2 = (const float*)d_in[11];
  const float* adaln_w = (const float*)d_in[12];
  const float* adaln_b = (const float*)d_in[13];
  const float* qkv_w = (const float*)d_in[14];
  const float* qkv_b = (const float*)d_in[15];
  const float* op_w = (const float*)d_in[16];
  const float* op_b = (const float*)d_in[17];
  const float* ffn_w1 = (const float*)d_in[18];
  const float* ffn_b1 = (const float*)d_in[19];
  const float* ffn_w2 = (const float*)d_in[20];
  const float* ffn_b2 = (const float*)d_in[21];
  const float* fa_w = (const float*)d_in[22];
  const float* fa_b = (const float*)d_in[23];
  const float* fp_w = (const float*)d_in[24];
  const float* fp_b = (const float*)d_in[25];

  char* w = (char*)d_ws;
  auto alloc = [&](size_t bytes) { char* p = w; w += (bytes + 255) & ~(size_t)255; return p; };
  u16* WT_cp1 = (u16*)alloc(256L * 512 * 2);
  u16* WT_cp2 = (u16*)alloc(256L * 256 * 2);
  u16* WT_adaln = (u16*)alloc(6L * 1536 * 256 * 2);  // = [9216][256] B^T
  u16* WT_qkv = (u16*)alloc(6L * 768 * 256 * 2);
  u16* WT_op = (u16*)alloc(6L * 256 * 256 * 2);
  u16* WT_f1 = (u16*)alloc(6L * 512 * 256 * 2);
  u16* WT_f2 = (u16*)alloc(6L * 256 * 512 * 2);
  u16* WT_fa = (u16*)alloc(512L * 256 * 2);
  u16* WT_fp = (u16*)alloc(256L * 256 * 2);
  float* te_tab = (float*)alloc(21L * 256 * 4);
  u16* cond = (u16*)alloc(4096L * 512 * 2);
  u16* c1 = (u16*)alloc(4096L * 256 * 2);
  u16* mc = (u16*)alloc(4096L * 256 * 2);
  u16* modb6 = (u16*)alloc(4096L * 9216 * 2);  // batch-major [4096][6*1536]
  u16* famod = (u16*)alloc(4096L * 512 * 2);
  u16* hbuf = (u16*)alloc(BSr * 256 * 2);
  u16* qkvbuf = (u16*)alloc(BSr * 768 * 2);
  u16* xbuf = (u16*)d_out;  // bf16 residual stream in d_out storage

  transpose_w<<<dim3(4, 8, 1), 256, 0, stream>>>(cp_w1, WT_cp1, 512, 256);
  transpose_w<<<dim3(4, 4, 1), 256, 0, stream>>>(cp_w2, WT_cp2, 256, 256);
  transpose_w<<<dim3(24, 4, 6), 256, 0, stream>>>(adaln_w, WT_adaln, 256, 1536);
  transpose_w<<<dim3(12, 4, 6), 256, 0, stream>>>(qkv_w, WT_qkv, 256, 768);
  transpose_w<<<dim3(4, 4, 6), 256, 0, stream>>>(op_w, WT_op, 256, 256);
  transpose_w<<<dim3(8, 4, 6), 256, 0, stream>>>(ffn_w1, WT_f1, 256, 512);
  transpose_w<<<dim3(4, 8, 6), 256, 0, stream>>>(ffn_w2, WT_f2, 512, 256);
  transpose_w<<<dim3(8, 4, 1), 256, 0, stream>>>(fa_w, WT_fa, 256, 512);
  transpose_w<<<dim3(4, 4, 1), 256, 0, stream>>>(fp_w, WT_fp, 256, 256);

  te_table_kernel<<<21, 1024, 0, stream>>>(emb, te_w1, te_b1, te_w2, te_b2, te_tab);
  cond_mean_kernel<<<4096, 256, 0, stream>>>(backbone, cond);

  gemm_bt<1, true><<<dim3(2, 32), 256, 0, stream>>>(cond, WT_cp1, cp_b1, c1, nullptr, nullptr, 4096, 256, 512);
  gemm_bt<4, true><<<dim3(2, 32), 256, 0, stream>>>(c1, WT_cp2, cp_b2, mc, tvec, te_tab, 4096, 256, 256);
  gemm_bt<0, true><<<dim3(4, 32), 256, 0, stream>>>(mc, WT_fa, fa_b, famod, nullptr, nullptr, 4096, 512, 256);
  // single adaLN GEMM over all 6 layers: N = 6*1536 = 9216 (2304 blocks), XCD-swizzled
  gemm_bt<0, true><<<dim3(72, 32), 256, 0, stream>>>(mc, WT_adaln, adaln_b, modb6, nullptr, nullptr, 4096, 9216, 256);

  // layer-0 input LN (sh1/sc1)
  ln_mod<<<BSr / 4, 256, 0, stream>>>(x_t, modb6, 9216, 0, 256, hbuf);

  for (int l = 0; l < L; ++l) {
    const u16* mb = modb6 + (long)l * 1536;  // batch-major: row stride 9216
    // QKV GEMM with XCD-aware swizzle (6 N-blocks sharing an A-tile -> same XCD)
    gemm_bt<0, true><<<dim3(6, BSr / 128), 256, 0, stream>>>(hbuf, WT_qkv + (long)l * 768 * 256, qkv_b + l * 768,
                                                             qkvbuf, nullptr, nullptr, (int)BSr, 768, 256);
    attn_kernel<<<B * 2, 128, 0, stream>>>(qkvbuf, hbuf);
    // x = xin + g1*(attn_out @ Wop + b); h = LN(x)*(1+sc2)+sh2
    if (l == 0)
      gemm_ln<256, true><<<BSr / 64, 256, 0, stream>>>(hbuf, WT_op, op_b, x_t, mb + 512, 9216,
                                                       mb + 768, mb + 1024, 9216, xbuf, hbuf);
    else
      gemm_ln<256, false><<<BSr / 64, 256, 0, stream>>>(hbuf, WT_op + (long)l * 256 * 256, op_b + l * 256,
                                                        xbuf, mb + 512, 9216, mb + 768, mb + 1024, 9216, xbuf, hbuf);
    // fused FFN1+FFN2 + residual + next-layer LN (2 elems per block, pipelined)
    const u16* nsh = (l < 5) ? (mb + 1536) : famod;
    const u16* nsc = (l < 5) ? (mb + 1536 + 256) : (famod + 256);
    const int nstride = (l < 5) ? 9216 : 512;
    ffn_fused<<<BSr / 128, 512, 0, stream>>>(hbuf, WT_f1 + (long)l * 512 * 256, ffn_b1 + l * 512,
                                             WT_f2 + (long)l * 256 * 512, ffn_b2 + l * 256,
                                             xbuf, mb + 1280, 9216, nsh, nsc, nstride, xbuf, hbuf);
  }
  gemm_bt<3, true><<<dim3(2, BSr / 128), 256, 0, stream>>>(hbuf, WT_fp, fp_b, d_out, nullptr, nullptr, (int)BSr, 256, 256);
}